// Round 4
// baseline (1835.102 us; speedup 1.0000x reference)
//
#include <hip/hip_runtime.h>
#include <math.h>

static constexpr int NODES = 512;
static constexpr int CC    = 256;
static constexpr int KP    = 64;
static constexpr int ZDIM  = 513;

typedef unsigned short u16;
typedef short bf16x8 __attribute__((ext_vector_type(8)));
typedef float f32x4 __attribute__((ext_vector_type(4)));

__device__ __forceinline__ u16 f2b(float f){
  unsigned u = __float_as_uint(f);
  unsigned r = (u + 0x7FFF + ((u >> 16) & 1)) >> 16;
  return (u16)r;
}
__device__ __forceinline__ float b2f(u16 h){ return __uint_as_float(((unsigned)h) << 16); }
__device__ __forceinline__ f32x4 mfma16(bf16x8 a, bf16x8 b, f32x4 c){
  return __builtin_amdgcn_mfma_f32_16x16x32_bf16(a, b, c, 0, 0, 0);
}

// ======================= NN + patches (decision-exact) =======================
__global__ __launch_bounds__(256) void nn_kernel(const float* __restrict__ pts, int n,
                                                 const float* __restrict__ nodes,
                                                 int* __restrict__ out)
{
#pragma clang fp contract(off)
  __shared__ float nx[NODES], ny[NODES], nz[NODES], nn[NODES];
  for (int m = threadIdx.x; m < NODES; m += 256){
    float a = nodes[m*3+0], b = nodes[m*3+1], c = nodes[m*3+2];
    nx[m]=a; ny[m]=b; nz[m]=c;
    nn[m] = a*a + b*b + c*c;
  }
  __syncthreads();
  int i = blockIdx.x*256 + threadIdx.x;
  if (i >= n) return;
  float p0 = pts[i*3+0], p1 = pts[i*3+1], p2 = pts[i*3+2];
  float pp = p0*p0 + p1*p1 + p2*p2;
  float best = INFINITY; int bi = 0;
  for (int m = 0; m < NODES; ++m){
    float dot = fmaf(p2, nz[m], fmaf(p1, ny[m], p0*nx[m]));
    float d = (pp - 2.0f*dot) + nn[m];
    if (d < best){ best = d; bi = m; }
  }
  out[i] = bi;
}

__global__ __launch_bounds__(256) void hist_kernel(const int* __restrict__ id, int n,
                                                   int* __restrict__ hist)
{
  __shared__ int h[NODES];
  int t = threadIdx.x;
  h[t] = 0; h[t+256] = 0;
  __syncthreads();
  int i = blockIdx.x*256 + t;
  if (i < n) atomicAdd(&h[id[i]], 1);
  __syncthreads();
  hist[(long)blockIdx.x*NODES + t]       = h[t];
  hist[(long)blockIdx.x*NODES + t + 256] = h[t+256];
}

__global__ __launch_bounds__(512) void scan_kernel(int* __restrict__ hist, int nb,
                                                   int* __restrict__ counts)
{
  int m = threadIdx.x;
  int run = 0;
  for (int b = 0; b < nb; ++b){
    int t = hist[(long)b*NODES + m];
    hist[(long)b*NODES + m] = run;
    run += t;
  }
  counts[m] = run;
}

__global__ __launch_bounds__(256) void rank_kernel(const int* __restrict__ id, int n,
                                                   const int* __restrict__ hist,
                                                   int* __restrict__ patch)
{
  __shared__ int lid[256];
  int t = threadIdx.x;
  int i = blockIdx.x*256 + t;
  lid[t] = (i < n) ? id[i] : -1;
  __syncthreads();
  if (i >= n) return;
  int m = lid[t];
  int r = hist[(long)blockIdx.x*NODES + m];
  for (int q = 0; q < t; ++q) r += (lid[q] == m) ? 1 : 0;
  if (r < KP) patch[m*KP + r] = i;
}

// ======================= weight conversion =======================
__global__ __launch_bounds__(256) void conv_weights(
  const float* cwq, const float* cwk, const float* cwv, const float* cwm,
  const float* cw1, const float* cw2, const float* fpw,
  const float* lwq, const float* lwk, const float* lwv, const float* lwm,
  const float* lw1, const float* lw2, const float* lfp,
  u16* __restrict__ dst)
{
  int i = blockIdx.x*256 + threadIdx.x;
  if (i >= 2539520) return;
  const float* s; int off;
  if      (i <  196608){ s=cwq; off=0; }
  else if (i <  393216){ s=cwk; off=196608; }
  else if (i <  589824){ s=cwv; off=393216; }
  else if (i <  786432){ s=cwm; off=589824; }
  else if (i < 1572864){ s=cw1; off=786432; }
  else if (i < 1966080){ s=cw2; off=1572864; }
  else if (i < 2031616){ s=fpw; off=1966080; }
  else if (i < 2080768){ s=lwq; off=2031616; }
  else if (i < 2129920){ s=lwk; off=2080768; }
  else if (i < 2179072){ s=lwv; off=2129920; }
  else if (i < 2228224){ s=lwm; off=2179072; }
  else if (i < 2424832){ s=lw1; off=2228224; }
  else if (i < 2523136){ s=lw2; off=2424832; }
  else                 { s=lfp; off=2523136; }
  dst[i] = f2b(s[i - off]);
}

__global__ __launch_bounds__(256) void tr_in(const float* __restrict__ fs,
                                             const float* __restrict__ ft,
                                             u16* __restrict__ cf,
                                             float* __restrict__ cff)
{
  int i = blockIdx.x*256 + threadIdx.x;
  if (i >= 262144) return;
  int side = i >> 17; int r = i & 131071; int d = r >> 9; int n = r & 511;
  float v = (side ? ft : fs)[r];
  long o = ((long)side*512 + n)*256 + d;
  cf[o] = f2b(v);
  cff[o] = v;
}

// ======================= coarse transformer (bf16 MFMA, [n][d]) =======================
// qkv: grid 48: z -> side=z/24, rem=z%24, proj=rem>>3, slice=rem&7.
// Reads cf (old, both sides) BEFORE ffn overwrites — cross-safe.
__global__ __launch_bounds__(256) void coarse_qkv(
    const u16* __restrict__ cf, int cross,
    const u16* __restrict__ Wq, const u16* __restrict__ Wk, const u16* __restrict__ Wv,
    const float* __restrict__ bq, const float* __restrict__ bk, const float* __restrict__ bv,
    u16* __restrict__ qb, u16* __restrict__ kb, u16* __restrict__ vtb)
{
  int z = blockIdx.x;
  int side = z/24, rem = z%24, proj = rem >> 3, slice = rem & 7;
  const u16* x = cf + (long)side*131072;
  const u16* s = cross ? cf + (long)(1-side)*131072 : x;
  const u16* in = (proj == 0) ? x : s;
  const u16* W  = (proj==0)?Wq:(proj==1)?Wk:Wv;
  const float* bi = (proj==0)?bq:(proj==1)?bk:bv;
  int n0 = slice << 6;
  int wv_ = threadIdx.x >> 6, L = threadIdx.x & 63, lr = L & 15, lk = L >> 4;
  const u16* inb = in + (long)(n0 + lr)*256 + 8*lk;
  for (int oi = 0; oi < 4; ++oi){
    int o0 = (wv_*4 + oi) << 4;
    const u16* wrow = W + (long)(o0 + lr)*256 + 8*lk;
    f32x4 acc[4] = {};
#pragma unroll
    for (int ks = 0; ks < 8; ++ks){
      bf16x8 b = *(const bf16x8*)(wrow + ks*32);
#pragma unroll
      for (int a = 0; a < 4; ++a){
        bf16x8 av = *(const bf16x8*)(inb + a*16*256 + ks*32);
        acc[a] = mfma16(av, b, acc[a]);
      }
    }
    int col = o0 + lr;
    float bvv = bi[col];
    if (proj < 2){
      u16* o = (proj==0 ? qb : kb) + ((long)side*512 + n0)*256 + col;
#pragma unroll
      for (int a = 0; a < 4; ++a)
#pragma unroll
        for (int q_ = 0; q_ < 4; ++q_)
          o[(long)(a*16 + lk*4 + q_)*256] = f2b(acc[a][q_] + bvv);
    } else {
      u16* o = vtb + ((long)side*256 + col)*512 + n0;
#pragma unroll
      for (int a = 0; a < 4; ++a)
#pragma unroll
        for (int q_ = 0; q_ < 4; ++q_)
          o[a*16 + lk*4 + q_] = f2b(acc[a][q_] + bvv);
    }
  }
}

// attn: grid 64: z -> side=z/32, rem: head=(rem>>3), qs=rem&7
__global__ __launch_bounds__(256) void coarse_attn(
    const u16* __restrict__ qb, const u16* __restrict__ kb,
    const u16* __restrict__ vtb, u16* __restrict__ msgb)
{
  __shared__ u16 P[64][512];
  __shared__ float rmx[64][4], rsm[64][4];
  int z = blockIdx.x;
  int side = (z >> 5); int rem = z & 31;
  int head = rem >> 3, qs = rem & 7;
  int wv_ = threadIdx.x >> 6, L = threadIdx.x & 63, lr = L & 15, lk = L >> 4;
  const u16* q = qb + ((long)side*512 + qs*64)*256 + head*64;
  const u16* k = kb + (long)side*512*256 + head*64;
  const u16* vt = vtb + ((long)side*256 + head*64)*512;

  bf16x8 af[4][2];
#pragma unroll
  for (int a = 0; a < 4; ++a)
#pragma unroll
    for (int ks = 0; ks < 2; ++ks)
      af[a][ks] = *(const bf16x8*)(q + (long)(a*16 + lr)*256 + ks*32 + 8*lk);

  f32x4 sc[4][8] = {};
  for (int b = 0; b < 8; ++b){
    const u16* krow = k + (long)(wv_*128 + b*16 + lr)*256 + 8*lk;
#pragma unroll
    for (int ks = 0; ks < 2; ++ks){
      bf16x8 bf = *(const bf16x8*)(krow + ks*32);
#pragma unroll
      for (int a = 0; a < 4; ++a)
        sc[a][b] = mfma16(af[a][ks], bf, sc[a][b]);
    }
  }
  const float SC = 0.125f; // 1/sqrt(64)
#pragma unroll
  for (int a = 0; a < 4; ++a)
#pragma unroll
    for (int q_ = 0; q_ < 4; ++q_){
      float m = sc[a][0][q_];
#pragma unroll
      for (int b = 1; b < 8; ++b) m = fmaxf(m, sc[a][b][q_]);
      m = fmaxf(m, __shfl_xor(m, 1)); m = fmaxf(m, __shfl_xor(m, 2));
      m = fmaxf(m, __shfl_xor(m, 4)); m = fmaxf(m, __shfl_xor(m, 8));
      if (lr == 0) rmx[a*16 + lk*4 + q_][wv_] = m;
    }
  __syncthreads();
#pragma unroll
  for (int a = 0; a < 4; ++a)
#pragma unroll
    for (int q_ = 0; q_ < 4; ++q_){
      int row = a*16 + lk*4 + q_;
      float m = fmaxf(fmaxf(rmx[row][0], rmx[row][1]), fmaxf(rmx[row][2], rmx[row][3]));
      float s = 0.f;
#pragma unroll
      for (int b = 0; b < 8; ++b){
        float e = __expf((sc[a][b][q_] - m)*SC);
        sc[a][b][q_] = e; s += e;
      }
      s += __shfl_xor(s,1); s += __shfl_xor(s,2); s += __shfl_xor(s,4); s += __shfl_xor(s,8);
      if (lr == 0) rsm[row][wv_] = s;
    }
  __syncthreads();
#pragma unroll
  for (int a = 0; a < 4; ++a)
#pragma unroll
    for (int q_ = 0; q_ < 4; ++q_){
      int row = a*16 + lk*4 + q_;
      float inv = 1.f / (rsm[row][0]+rsm[row][1]+rsm[row][2]+rsm[row][3]);
#pragma unroll
      for (int b = 0; b < 8; ++b)
        P[row][wv_*128 + b*16 + lr] = f2b(sc[a][b][q_] * inv);
    }
  __syncthreads();
  f32x4 mv[4] = {};
  for (int ks = 0; ks < 16; ++ks){
    bf16x8 bf = *(const bf16x8*)(vt + (long)(wv_*16 + lr)*512 + ks*32 + 8*lk);
#pragma unroll
    for (int a = 0; a < 4; ++a){
      bf16x8 av = *(const bf16x8*)(&P[a*16 + lr][ks*32 + 8*lk]);
      mv[a] = mfma16(av, bf, mv[a]);
    }
  }
  u16* o = msgb + ((long)side*512 + qs*64)*256 + head*64 + wv_*16 + lr;
#pragma unroll
  for (int a = 0; a < 4; ++a)
#pragma unroll
    for (int q_ = 0; q_ < 4; ++q_)
      o[(long)(a*16 + lk*4 + q_)*256] = f2b(mv[a][q_]);
}

// ffn: grid 16, 512 threads: z -> side=z/8, slice=z&7
__global__ __launch_bounds__(512) void coarse_ffn(
    const u16* __restrict__ msgb, u16* __restrict__ cf, float* __restrict__ cff,
    const u16* __restrict__ Wm, const float* __restrict__ bm,
    const u16* __restrict__ W1, const float* __restrict__ b1,
    const u16* __restrict__ W2, const float* __restrict__ b2)
{
  __shared__ u16 m2[64*256];
  __shared__ u16 h1[64*512];
  int z = blockIdx.x;
  int side = (z >> 3), slice = z & 7;
  int wv_ = threadIdx.x >> 6, L = threadIdx.x & 63, lr = L & 15, lk = L >> 4;
  const u16* msg = msgb + ((long)side*512 + slice*64)*256;
  u16* x = cf + ((long)side*512 + slice*64)*256;
  float* xf = cff + ((long)side*512 + slice*64)*256;
  for (int oi = 0; oi < 2; ++oi){
    int o0 = (wv_*2 + oi) << 4;
    f32x4 acc[4] = {};
    const u16* wrow = Wm + (long)(o0+lr)*256 + 8*lk;
#pragma unroll
    for (int ks = 0; ks < 8; ++ks){
      bf16x8 b = *(const bf16x8*)(wrow + ks*32);
#pragma unroll
      for (int a = 0; a < 4; ++a){
        bf16x8 av = *(const bf16x8*)(msg + (long)(a*16+lr)*256 + ks*32 + 8*lk);
        acc[a] = mfma16(av, b, acc[a]);
      }
    }
    int col = o0 + lr; float bb = bm[col];
#pragma unroll
    for (int a = 0; a < 4; ++a)
#pragma unroll
      for (int q_ = 0; q_ < 4; ++q_)
        m2[(a*16+lk*4+q_)*256 + col] = f2b(acc[a][q_] + bb);
  }
  __syncthreads();
  for (int oi = 0; oi < 4; ++oi){
    int o0 = (wv_*4 + oi) << 4;
    f32x4 acc[4] = {};
    const u16* wrow = W1 + (long)(o0+lr)*512 + 8*lk;
#pragma unroll
    for (int ks = 0; ks < 16; ++ks){
      int kk = ks*32;
      bf16x8 b = *(const bf16x8*)(wrow + kk);
#pragma unroll
      for (int a = 0; a < 4; ++a){
        bf16x8 av;
        if (kk < 256) av = *(const bf16x8*)(x + (long)(a*16+lr)*256 + kk + 8*lk);
        else          av = *(const bf16x8*)(&m2[(a*16+lr)*256 + kk - 256 + 8*lk]);
        acc[a] = mfma16(av, b, acc[a]);
      }
    }
    int col = o0 + lr; float bb = b1[col];
#pragma unroll
    for (int a = 0; a < 4; ++a)
#pragma unroll
      for (int q_ = 0; q_ < 4; ++q_)
        h1[(a*16+lk*4+q_)*512 + col] = f2b(fmaxf(acc[a][q_] + bb, 0.f));
  }
  __syncthreads();
  for (int oi = 0; oi < 2; ++oi){
    int o0 = (wv_*2 + oi) << 4;
    f32x4 acc[4] = {};
    const u16* wrow = W2 + (long)(o0+lr)*512 + 8*lk;
#pragma unroll
    for (int ks = 0; ks < 16; ++ks){
      bf16x8 b = *(const bf16x8*)(wrow + ks*32);
#pragma unroll
      for (int a = 0; a < 4; ++a){
        bf16x8 av = *(const bf16x8*)(&h1[(a*16+lr)*512 + ks*32 + 8*lk]);
        acc[a] = mfma16(av, b, acc[a]);
      }
    }
    int col = o0 + lr; float bb = b2[col];
#pragma unroll
    for (int a = 0; a < 4; ++a)
#pragma unroll
      for (int q_ = 0; q_ < 4; ++q_){
        long idx = (long)(a*16+lk*4+q_)*256 + col;
        float v = acc[a][q_] + bb + xf[idx];
        xf[idx] = v;
        x[idx] = f2b(v);
      }
  }
}

__global__ __launch_bounds__(256) void coarse_proj(
    const u16* __restrict__ cf, const u16* __restrict__ W,
    const float* __restrict__ bias, u16* __restrict__ out)
{
  int z = blockIdx.x;
  int side = z >> 3, slice = z & 7;
  const u16* in = cf + (long)side*131072;
  u16* o = out + (long)side*131072;
  int n0 = slice << 6;
  int wv_ = threadIdx.x >> 6, L = threadIdx.x & 63, lr = L & 15, lk = L >> 4;
  const u16* inb = in + (long)(n0 + lr)*256 + 8*lk;
  for (int oi = 0; oi < 4; ++oi){
    int o0 = (wv_*4 + oi) << 4;
    const u16* wrow = W + (long)(o0 + lr)*256 + 8*lk;
    f32x4 acc[4] = {};
#pragma unroll
    for (int ks = 0; ks < 8; ++ks){
      bf16x8 b = *(const bf16x8*)(wrow + ks*32);
#pragma unroll
      for (int a = 0; a < 4; ++a){
        bf16x8 av = *(const bf16x8*)(inb + a*16*256 + ks*32);
        acc[a] = mfma16(av, b, acc[a]);
      }
    }
    int col = o0 + lr; float bb = bias[col];
#pragma unroll
    for (int a = 0; a < 4; ++a)
#pragma unroll
      for (int q_ = 0; q_ < 4; ++q_)
        o[(long)(n0 + a*16 + lk*4 + q_)*256 + col] = f2b(acc[a][q_] + bb);
  }
}

__global__ __launch_bounds__(256) void coarse_scores(
    const u16* __restrict__ sfp, const u16* __restrict__ tfp, float* __restrict__ Z)
{
  int n0 = blockIdx.y << 6, m0 = blockIdx.x << 6;
  int wv_ = threadIdx.x >> 6, L = threadIdx.x & 63, lr = L & 15, lk = L >> 4;
  f32x4 acc[4] = {};
  const u16* arow = sfp + (long)(n0 + lr)*256 + 8*lk;
  const u16* brow = tfp + (long)(m0 + wv_*16 + lr)*256 + 8*lk;
#pragma unroll
  for (int ks = 0; ks < 8; ++ks){
    bf16x8 b = *(const bf16x8*)(brow + ks*32);
#pragma unroll
    for (int a = 0; a < 4; ++a){
      bf16x8 av = *(const bf16x8*)(arow + a*16*256 + ks*32);
      acc[a] = mfma16(av, b, acc[a]);
    }
  }
  int col = m0 + wv_*16 + lr;
#pragma unroll
  for (int a = 0; a < 4; ++a)
#pragma unroll
    for (int q_ = 0; q_ < 4; ++q_)
      Z[(long)(n0 + a*16 + lk*4 + q_)*513 + col] = acc[a][q_]*0.0625f;
}

// ======================= transport =======================
__global__ __launch_bounds__(256) void fill_border(float* Z, const float* __restrict__ alpha)
{
  int i = blockIdx.x*256 + threadIdx.x;
  if (i < ZDIM){
    float a = alpha[0];
    Z[(long)i*ZDIM + (ZDIM-1)] = a;
    Z[(long)(ZDIM-1)*ZDIM + i] = a;
  }
}

__global__ __launch_bounds__(256) void transpose_k(const float* __restrict__ A,
                                                   float* __restrict__ B, int n)
{
  __shared__ float t[32][33];
  int bx = blockIdx.x*32, by = blockIdx.y*32;
  int lx = threadIdx.x & 31, ly0 = threadIdx.x >> 5;
  for (int dy = 0; dy < 32; dy += 8){
    int x = bx + lx, y = by + ly0 + dy;
    if (x < n && y < n) t[ly0+dy][lx] = A[(long)y*n + x];
  }
  __syncthreads();
  for (int dy = 0; dy < 32; dy += 8){
    int x = by + lx, y = bx + ly0 + dy;
    if (x < n && y < n) B[(long)y*n + x] = t[lx][ly0+dy];
  }
}

// persistent exp-domain sinkhorn: 16 blocks, LDS-resident slices, spin grid barrier
static constexpr int TPNB = 16;
static constexpr int TPROWS = 33;

__device__ __forceinline__ void gbar(int* bar, int ph){
  __syncthreads();
  if (threadIdx.x == 0){
    __threadfence();
    int bid = blockIdx.x;
    __hip_atomic_store(&bar[bid+1], ph, __ATOMIC_RELEASE, __HIP_MEMORY_SCOPE_AGENT);
    if (bid == 0){
      for (int i = 1; i < TPNB; ++i)
        while (__hip_atomic_load(&bar[i+1], __ATOMIC_ACQUIRE, __HIP_MEMORY_SCOPE_AGENT) < ph)
          __builtin_amdgcn_s_sleep(1);
      __hip_atomic_store(&bar[0], ph, __ATOMIC_RELEASE, __HIP_MEMORY_SCOPE_AGENT);
    } else {
      while (__hip_atomic_load(&bar[0], __ATOMIC_ACQUIRE, __HIP_MEMORY_SCOPE_AGENT) < ph)
        __builtin_amdgcn_s_sleep(1);
    }
  }
  __syncthreads();
}

__global__ __launch_bounds__(1024) void transport_persist(
    const float* __restrict__ Z, const float* __restrict__ Zt,
    float* __restrict__ Rr, float* __restrict__ Cc,
    float* __restrict__ wu, float* __restrict__ wvv,
    float* __restrict__ out, int* bar, float outadd)
{
  __shared__ float A[TPROWS*513];
  __shared__ float B[TPROWS*513];
  __shared__ float vl[513];
  int bid = blockIdx.x, tid = threadIdx.x;
  int wv_ = tid >> 6, lane = tid & 63;
  int r0 = bid * TPROWS;
  int nr = 513 - r0; if (nr > TPROWS) nr = TPROWS;
  for (int i = wv_; i < nr; i += 16){
    const float* zr  = Z  + (long)(r0+i)*513;
    const float* ztr = Zt + (long)(r0+i)*513;
    for (int j = lane; j < 513; j += 64){ A[i*513+j] = zr[j]; B[i*513+j] = ztr[j]; }
  }
  __syncthreads();
  for (int i = wv_; i < nr; i += 16){
    float m = -INFINITY;
    for (int j = lane; j < 513; j += 64) m = fmaxf(m, A[i*513+j]);
    for (int o = 32; o; o >>= 1) m = fmaxf(m, __shfl_xor(m, o));
    if (lane == 0) Rr[r0+i] = m;
  }
  gbar(bar, 1);
  for (int i = wv_; i < nr; i += 16){
    float m = -INFINITY;
    for (int j = lane; j < 513; j += 64) m = fmaxf(m, B[i*513+j] - Rr[j]);
    for (int o = 32; o; o >>= 1) m = fmaxf(m, __shfl_xor(m, o));
    if (lane == 0) Cc[r0+i] = m;
  }
  gbar(bar, 2);
  for (int i = wv_; i < nr; i += 16){
    float ro = Rr[r0+i], co = Cc[r0+i];
    for (int j = lane; j < 513; j += 64){
      A[i*513+j] = __expf(A[i*513+j] - ro - Cc[j]);
      B[i*513+j] = __expf(B[i*513+j] - co - Rr[j]);
    }
  }
  __syncthreads();
  const float EBM = 1.0f/1024.0f, EBL = 0.5f;
  int ph = 2;
  for (int it = 0; it < 50; ++it){
    for (int i = wv_; i < nr; i += 16){
      float s = 0.f;
      if (it == 0){ for (int j = lane; j < 513; j += 64) s += A[i*513+j]; }
      else        { for (int j = lane; j < 513; j += 64) s = fmaf(A[i*513+j], wvv[j], s); }
      for (int o = 32; o; o >>= 1) s += __shfl_xor(s, o);
      if (lane == 0){ int r = r0+i; wu[r] = ((r < 512) ? EBM : EBL) / s; }
    }
    gbar(bar, ++ph);
    for (int i = wv_; i < nr; i += 16){
      float s = 0.f;
      for (int j = lane; j < 513; j += 64) s = fmaf(B[i*513+j], wu[j], s);
      for (int o = 32; o; o >>= 1) s += __shfl_xor(s, o);
      if (lane == 0){ int r = r0+i; wvv[r] = ((r < 512) ? EBM : EBL) / s; }
    }
    gbar(bar, ++ph);
  }
  for (int c = tid; c < 513; c += 1024) vl[c] = __logf(wvv[c]) - Cc[c];
  __syncthreads();
  for (int i = wv_; i < nr; i += 16){
    int r = r0 + i;
    float uu = __logf(wu[r]) - Rr[r];
    const float* zr = Z + (long)r*513;
    float* orow = out + (long)r*513;
    for (int j = lane; j < 513; j += 64) orow[j] = zr[j] + uu + vl[j] + outadd;
  }
}

// ======================= local gather (bf16 [c][n][d]) =======================
__global__ __launch_bounds__(256) void gather_feats(const float* __restrict__ F,
                                                    const int* __restrict__ patch,
                                                    const int* __restrict__ corr,
                                                    int side, u16* __restrict__ out)
{
  int c = blockIdx.x;
  __shared__ int sel[KP];
  int tid = threadIdx.x;
  if (tid < KP){
    int node = corr[c*2 + side];
    sel[tid] = patch[node*KP + tid];
  }
  __syncthreads();
  for (int e = tid; e < KP*128; e += 256){
    int n = e >> 7, d = e & 127;
    out[((long)c*KP + n)*128 + d] = f2b(F[(long)sel[n]*128 + d]);
  }
}

// ======================= fused local transformer layer (ping-pong) =======================
__global__ __launch_bounds__(256) void local_layer(
    const u16* __restrict__ Xin, u16* __restrict__ Xout, int cross,
    const u16* __restrict__ Wq, const u16* __restrict__ Wk,
    const u16* __restrict__ Wv, const u16* __restrict__ Wm,
    const u16* __restrict__ W1, const u16* __restrict__ W2,
    const float* __restrict__ bq, const float* __restrict__ bk,
    const float* __restrict__ bv, const float* __restrict__ bm,
    const float* __restrict__ b1, const float* __restrict__ b2)
{
  __shared__ u16 pool[32768];
  int z = blockIdx.x;
  int side = (z >> 8), c = z & 255;
  const u16* x = Xin + ((long)side*256 + c)*8192;
  const u16* s = Xin + ((long)(cross ? 1-side : side)*256 + c)*8192;
  u16* xo = Xout + ((long)side*256 + c)*8192;
  int wv_ = threadIdx.x >> 6, L = threadIdx.x & 63, lr = L & 15, lk = L >> 4;
  u16* qS = pool; u16* kS = pool + 8192; u16* vT = pool + 16384; u16* msgS = pool + 24576;

#pragma unroll
  for (int proj = 0; proj < 3; ++proj){
    const u16* in = proj ? s : x;
    const u16* W = proj==0?Wq:proj==1?Wk:Wv;
    const float* bi = proj==0?bq:proj==1?bk:bv;
#pragma unroll
    for (int oi = 0; oi < 2; ++oi){
      int o0 = (wv_ + oi*4) << 4;
      f32x4 acc[4] = {};
      const u16* wrow = W + (long)(o0+lr)*128 + 8*lk;
      const u16* inr = in + (long)lr*128 + 8*lk;
#pragma unroll
      for (int ks = 0; ks < 4; ++ks){
        bf16x8 b = *(const bf16x8*)(wrow + ks*32);
#pragma unroll
        for (int a = 0; a < 4; ++a){
          bf16x8 av = *(const bf16x8*)(inr + a*16*128 + ks*32);
          acc[a] = mfma16(av, b, acc[a]);
        }
      }
      int col = o0 + lr; float bb = bi[col];
      if (proj < 2){
        u16* dst = (proj==0 ? qS : kS);
#pragma unroll
        for (int a = 0; a < 4; ++a)
#pragma unroll
          for (int q_ = 0; q_ < 4; ++q_)
            dst[(a*16 + lk*4 + q_)*128 + col] = f2b(acc[a][q_] + bb);
      } else {
#pragma unroll
        for (int a = 0; a < 4; ++a)
#pragma unroll
          for (int q_ = 0; q_ < 4; ++q_)
            vT[col*64 + a*16 + lk*4 + q_] = f2b(acc[a][q_] + bb);
      }
    }
  }
  __syncthreads();
  int h = wv_;
  bf16x8 qf[4], kf[4];
#pragma unroll
  for (int a = 0; a < 4; ++a){
    qf[a] = *(const bf16x8*)(&qS[(a*16+lr)*128 + h*32 + 8*lk]);
    kf[a] = *(const bf16x8*)(&kS[(a*16+lr)*128 + h*32 + 8*lk]);
  }
  f32x4 sc[4][4] = {};
#pragma unroll
  for (int b = 0; b < 4; ++b)
#pragma unroll
    for (int a = 0; a < 4; ++a)
      sc[a][b] = mfma16(qf[a], kf[b], sc[a][b]);
  const float SCs = 0.17677669529663687f;
  float invs[4][4];
#pragma unroll
  for (int a = 0; a < 4; ++a)
#pragma unroll
    for (int q_ = 0; q_ < 4; ++q_){
      float m = sc[a][0][q_];
#pragma unroll
      for (int b = 1; b < 4; ++b) m = fmaxf(m, sc[a][b][q_]);
      m = fmaxf(m, __shfl_xor(m, 1)); m = fmaxf(m, __shfl_xor(m, 2));
      m = fmaxf(m, __shfl_xor(m, 4)); m = fmaxf(m, __shfl_xor(m, 8));
      float ss = 0.f;
#pragma unroll
      for (int b = 0; b < 4; ++b){
        float e = __expf((sc[a][b][q_] - m)*SCs);
        sc[a][b][q_] = e; ss += e;
      }
      ss += __shfl_xor(ss,1); ss += __shfl_xor(ss,2); ss += __shfl_xor(ss,4); ss += __shfl_xor(ss,8);
      invs[a][q_] = 1.f/ss;
    }
  __syncthreads();
  u16* P = pool + h*4096;
#pragma unroll
  for (int a = 0; a < 4; ++a)
#pragma unroll
    for (int q_ = 0; q_ < 4; ++q_)
#pragma unroll
      for (int b = 0; b < 4; ++b)
        P[(a*16 + lk*4 + q_)*64 + b*16 + lr] = f2b(sc[a][b][q_] * invs[a][q_]);
  f32x4 mv[4][2] = {};
#pragma unroll
  for (int ks = 0; ks < 2; ++ks)
#pragma unroll
    for (int bt = 0; bt < 2; ++bt){
      bf16x8 bf = *(const bf16x8*)(&vT[(h*32 + bt*16 + lr)*64 + ks*32 + 8*lk]);
#pragma unroll
      for (int a = 0; a < 4; ++a){
        bf16x8 av = *(const bf16x8*)(&P[(a*16+lr)*64 + ks*32 + 8*lk]);
        mv[a][bt] = mfma16(av, bf, mv[a][bt]);
      }
    }
#pragma unroll
  for (int a = 0; a < 4; ++a)
#pragma unroll
    for (int bt = 0; bt < 2; ++bt)
#pragma unroll
      for (int q_ = 0; q_ < 4; ++q_)
        msgS[(a*16 + lk*4 + q_)*128 + h*32 + bt*16 + lr] = f2b(mv[a][bt][q_]);
  __syncthreads();
  u16* m2 = pool;
#pragma unroll
  for (int oi = 0; oi < 2; ++oi){
    int o0 = (wv_ + oi*4) << 4;
    f32x4 acc[4] = {};
    const u16* wrow = Wm + (long)(o0+lr)*128 + 8*lk;
#pragma unroll
    for (int ks = 0; ks < 4; ++ks){
      bf16x8 b = *(const bf16x8*)(wrow + ks*32);
#pragma unroll
      for (int a = 0; a < 4; ++a){
        bf16x8 av = *(const bf16x8*)(&msgS[(a*16+lr)*128 + ks*32 + 8*lk]);
        acc[a] = mfma16(av, b, acc[a]);
      }
    }
    int col = o0+lr; float bb = bm[col];
#pragma unroll
    for (int a = 0; a < 4; ++a)
#pragma unroll
      for (int q_ = 0; q_ < 4; ++q_)
        m2[(a*16+lk*4+q_)*128 + col] = f2b(acc[a][q_] + bb);
  }
  __syncthreads();
  u16* h1 = pool + 8192;
#pragma unroll
  for (int oi = 0; oi < 4; ++oi){
    int o0 = (wv_*4 + oi) << 4;
    f32x4 acc[4] = {};
    const u16* wrow = W1 + (long)(o0+lr)*256 + 8*lk;
#pragma unroll
    for (int ks = 0; ks < 8; ++ks){
      int kk = ks*32;
      bf16x8 b = *(const bf16x8*)(wrow + kk);
#pragma unroll
      for (int a = 0; a < 4; ++a){
        bf16x8 av;
        if (kk < 128) av = *(const bf16x8*)(x + (long)(a*16+lr)*128 + kk + 8*lk);
        else          av = *(const bf16x8*)(&m2[(a*16+lr)*128 + kk - 128 + 8*lk]);
        acc[a] = mfma16(av, b, acc[a]);
      }
    }
    int col = o0+lr; float bb = b1[col];
#pragma unroll
    for (int a = 0; a < 4; ++a)
#pragma unroll
      for (int q_ = 0; q_ < 4; ++q_)
        h1[(a*16+lk*4+q_)*256 + col] = f2b(fmaxf(acc[a][q_] + bb, 0.f));
  }
  __syncthreads();
#pragma unroll
  for (int oi = 0; oi < 2; ++oi){
    int o0 = (wv_ + oi*4) << 4;
    f32x4 acc[4] = {};
    const u16* wrow = W2 + (long)(o0+lr)*256 + 8*lk;
#pragma unroll
    for (int ks = 0; ks < 8; ++ks){
      bf16x8 b = *(const bf16x8*)(wrow + ks*32);
#pragma unroll
      for (int a = 0; a < 4; ++a){
        bf16x8 av = *(const bf16x8*)(&h1[(a*16+lr)*256 + ks*32 + 8*lk]);
        acc[a] = mfma16(av, b, acc[a]);
      }
    }
    int col = o0+lr; float bb = b2[col];
#pragma unroll
    for (int a = 0; a < 4; ++a)
#pragma unroll
      for (int q_ = 0; q_ < 4; ++q_){
        int ri = (a*16+lk*4+q_)*128 + col;
        xo[ri] = f2b(acc[a][q_] + bb + b2f(x[ri]));
      }
  }
}

// ======================= fused lfp + scores + multiplicative sinkhorn =======================
__global__ __launch_bounds__(1024) void sk_fused(
    const u16* __restrict__ X, const u16* __restrict__ lfpW, const float* __restrict__ lfpB,
    const int* __restrict__ corr, const int* __restrict__ cnt_s,
    const int* __restrict__ cnt_t, float* __restrict__ out)
{
  __shared__ u16 sptp[16384];        // 32KB; E (65*66 f32 = 17160B) overlays it after scores
  __shared__ float LA[65][66];
  __shared__ float ET[65*66];
  __shared__ float uvec[65], vvec[65], u0s[65], Ul[65], Vl[65];
  float* E = (float*)sptp;
  u16* sp = sptp; u16* tp = sptp + 8192;
  int cpat = blockIdx.x;
  int tid = threadIdx.x;
  int wv_ = tid >> 6, L = tid & 63, lr = L & 15, lk = L >> 4;

  // lfp projection
  {
    const u16* in = X + ((long)((wv_>>3)*256 + cpat))*8192;
    u16* dst = (wv_ < 8) ? sp : tp;
    int o0 = (wv_ & 7) << 4;
    f32x4 acc[4] = {};
    const u16* wrow = lfpW + (long)(o0+lr)*128 + 8*lk;
    const u16* inr = in + (long)lr*128 + 8*lk;
#pragma unroll
    for (int ks = 0; ks < 4; ++ks){
      bf16x8 b = *(const bf16x8*)(wrow + ks*32);
#pragma unroll
      for (int a = 0; a < 4; ++a){
        bf16x8 av = *(const bf16x8*)(inr + a*16*128 + ks*32);
        acc[a] = mfma16(av, b, acc[a]);
      }
    }
    int col = o0 + lr; float bb = lfpB[col];
#pragma unroll
    for (int a = 0; a < 4; ++a)
#pragma unroll
      for (int q_ = 0; q_ < 4; ++q_)
        dst[(a*16 + lk*4 + q_)*128 + col] = f2b(acc[a][q_] + bb);
  }
  __syncthreads();
  int cs = cnt_s[corr[cpat*2]], ct = cnt_t[corr[cpat*2+1]];
  // scores -> LA (masked)
  {
    int mt = wv_ >> 2, nt = wv_ & 3;
    f32x4 acc = {};
    const u16* arow = sp + (mt*16 + lr)*128 + 8*lk;
    const u16* brow = tp + (nt*16 + lr)*128 + 8*lk;
#pragma unroll
    for (int ks = 0; ks < 4; ++ks){
      bf16x8 a = *(const bf16x8*)(arow + ks*32);
      bf16x8 b = *(const bf16x8*)(brow + ks*32);
      acc = mfma16(a, b, acc);
    }
    const float SCS = 0.08838834764831845f;
#pragma unroll
    for (int q_ = 0; q_ < 4; ++q_){
      int row = mt*16 + lk*4 + q_;
      int col = nt*16 + lr;
      float v = acc[q_] * SCS;
      if (row >= cs || col >= ct) v = -1000000.0f;
      LA[row][col] = v;
    }
  }
  if (tid < 65){ LA[64][tid] = 0.f; LA[tid][64] = 0.f; uvec[tid] = 1.f; vvec[tid] = 1.f; }
  __syncthreads();
  int g = tid >> 4, sub = tid & 15;
  // initial row pass (log domain), build E and E^T (E overlays sp/tp region)
  {
    float mx = -INFINITY;
    for (int j = sub; j < 65; j += 16) mx = fmaxf(mx, LA[g][j]);
    mx = fmaxf(mx, __shfl_xor(mx, 1)); mx = fmaxf(mx, __shfl_xor(mx, 2));
    mx = fmaxf(mx, __shfl_xor(mx, 4)); mx = fmaxf(mx, __shfl_xor(mx, 8));
    float s = 0.f;
    for (int j = sub; j < 65; j += 16) s += __expf(LA[g][j] - mx);
    s += __shfl_xor(s,1); s += __shfl_xor(s,2); s += __shfl_xor(s,4); s += __shfl_xor(s,8);
    float u0 = mx + __logf(s);
    if (sub == 0) u0s[g] = u0;
    for (int j = sub; j < 65; j += 16){
      float e = __expf(LA[g][j] - u0);
      E[g*66 + j] = e;
      ET[j*66 + g] = e;
    }
  }
  if (tid < 65){
    E[64*66 + tid] = 1.f;
    ET[tid*66 + 64] = 1.f;
    if (tid == 64) u0s[64] = 0.f;
  }
  __syncthreads();
  // 50 x (col phase, row phase), ending on col phase
  for (int it = 0; it < 50; ++it){
    {
      float s = 0.f;
      for (int r = sub; r < 65; r += 16) s = fmaf(ET[g*66 + r], uvec[r], s);
      s += __shfl_xor(s,1); s += __shfl_xor(s,2); s += __shfl_xor(s,4); s += __shfl_xor(s,8);
      if (sub == 0) vvec[g] = 1.f / s;
    }
    __syncthreads();
    if (it == 49) break;
    {
      float s = 0.f;
      for (int j = sub; j < 65; j += 16) s = fmaf(E[g*66 + j], vvec[j], s);
      s += __shfl_xor(s,1); s += __shfl_xor(s,2); s += __shfl_xor(s,4); s += __shfl_xor(s,8);
      if (sub == 0) uvec[g] = 1.f / s;
    }
    __syncthreads();
  }
  __syncthreads();
  if (tid < 65){ Ul[tid] = u0s[tid] - __logf(uvec[tid]); Vl[tid] = -__logf(vvec[tid]); }
  __syncthreads();
  for (int e = tid; e < 4225; e += 1024){
    int r = e / 65, c2 = e % 65;
    out[(long)cpat*4225 + e] = LA[r][c2] - Ul[r] - Vl[c2];
  }
}

// ======================= GT (decision-exact) =======================
__global__ __launch_bounds__(256) void gt_kernel(const float* __restrict__ sraw,
                                                 const float* __restrict__ traw,
                                                 const float* __restrict__ rot,
                                                 const float* __restrict__ trans,
                                                 const int* __restrict__ patch_s,
                                                 const int* __restrict__ patch_t,
                                                 const int* __restrict__ corr,
                                                 const int* __restrict__ cnt_s,
                                                 const int* __restrict__ cnt_t,
                                                 float* __restrict__ out)
{
#pragma clang fp contract(off)
  int c = blockIdx.x, tid = threadIdx.x;
  int sn = corr[c*2], tn = corr[c*2+1];
  int cs = cnt_s[sn], ct = cnt_t[tn];
  __shared__ float sx[64], sy[64], sz[64], spp[64];
  __shared__ float txa[64], tya[64], tza[64], tpp[64];
  __shared__ float g[64][65];
  __shared__ float rowsum[64], colsum[64];
  if (tid < 64){
    int idx = patch_s[sn*KP + tid];
    float p0 = sraw[(long)idx*3], p1 = sraw[(long)idx*3+1], p2 = sraw[(long)idx*3+2];
    float a0 = fmaf(rot[2], p2, fmaf(rot[1], p1, rot[0]*p0)) + trans[0];
    float a1 = fmaf(rot[5], p2, fmaf(rot[4], p1, rot[3]*p0)) + trans[1];
    float a2 = fmaf(rot[8], p2, fmaf(rot[7], p1, rot[6]*p0)) + trans[2];
    sx[tid]=a0; sy[tid]=a1; sz[tid]=a2;
    spp[tid] = a0*a0 + a1*a1 + a2*a2;
  } else if (tid < 128){
    int l = tid - 64;
    int idx = patch_t[tn*KP + l];
    float p0 = traw[(long)idx*3], p1 = traw[(long)idx*3+1], p2 = traw[(long)idx*3+2];
    txa[l]=p0; tya[l]=p1; tza[l]=p2;
    tpp[l] = p0*p0 + p1*p1 + p2*p2;
  }
  __syncthreads();
  for (int e = tid; e < 4096; e += 256){
    int n = e >> 6, m = e & 63;
    float dot = fmaf(sz[n], tza[m], fmaf(sy[n], tya[m], sx[n]*txa[m]));
    float d2 = (spp[n] + tpp[m]) - 2.0f*dot;
    d2 = fmaxf(d2, 0.f);
    g[n][m] = (sqrtf(d2) < 0.1f) ? 1.f : 0.f;
  }
  __syncthreads();
  if (tid < 64){
    float s = 0.f;
    for (int m = 0; m < 64; ++m) s += g[tid][m];
    rowsum[tid] = fmaxf(1.f - s, 0.f);
  } else if (tid < 128){
    int m = tid - 64;
    float s = 0.f;
    for (int n = 0; n < 64; ++n) s += g[n][m];
    colsum[m] = fmaxf(1.f - s, 0.f);
  }
  __syncthreads();
  float* o = out + (long)c*4225;
  for (int e = tid; e < 4225; e += 256){
    int r = e / 65, col = e % 65;
    float v;
    if (r < 64 && col < 64) v = g[r][col];
    else if (r < 64)        v = rowsum[r];
    else if (col < 64)      v = colsum[col];
    else                    v = 0.f;
    if (r < 64 && r >= cs)    v = 0.f;
    if (col < 64 && col >= ct) v = 0.f;
    o[e] = v;
  }
}

// ======================= host =======================
extern "C" void kernel_launch(void* const* d_in, const int* in_sizes, int n_in,
                              void* d_out, int out_size, void* d_ws, size_t ws_size,
                              hipStream_t stream)
{
  const float* src_pcd_c  = (const float*)d_in[0];
  const float* tgt_pcd_c  = (const float*)d_in[1];
  const float* src_node_c = (const float*)d_in[2];
  const float* tgt_node_c = (const float*)d_in[3];
  const float* src_feats  = (const float*)d_in[4];
  const float* tgt_feats  = (const float*)d_in[5];
  const float* src_final  = (const float*)d_in[6];
  const float* tgt_final  = (const float*)d_in[7];
  const float* rot        = (const float*)d_in[8];
  const float* trans      = (const float*)d_in[9];
  const float* src_raw    = (const float*)d_in[10];
  const float* tgt_raw    = (const float*)d_in[11];
  const int*   node_corr  = (const int*)d_in[12];
  const float* c_wq = (const float*)d_in[13]; const float* c_bq = (const float*)d_in[14];
  const float* c_wk = (const float*)d_in[15]; const float* c_bk = (const float*)d_in[16];
  const float* c_wv = (const float*)d_in[17]; const float* c_bv = (const float*)d_in[18];
  const float* c_wm = (const float*)d_in[19]; const float* c_bm = (const float*)d_in[20];
  const float* c_w1 = (const float*)d_in[21]; const float* c_b1 = (const float*)d_in[22];
  const float* c_w2 = (const float*)d_in[23]; const float* c_b2 = (const float*)d_in[24];
  const float* l_wq = (const float*)d_in[25]; const float* l_bq = (const float*)d_in[26];
  const float* l_wk = (const float*)d_in[27]; const float* l_bk = (const float*)d_in[28];
  const float* l_wv = (const float*)d_in[29]; const float* l_bv = (const float*)d_in[30];
  const float* l_wm = (const float*)d_in[31]; const float* l_bm = (const float*)d_in[32];
  const float* l_w1 = (const float*)d_in[33]; const float* l_b1 = (const float*)d_in[34];
  const float* l_w2 = (const float*)d_in[35]; const float* l_b2 = (const float*)d_in[36];
  const float* fp_w = (const float*)d_in[37]; const float* fp_b = (const float*)d_in[38];
  const float* lfp_w = (const float*)d_in[39]; const float* lfp_b = (const float*)d_in[40];
  const float* bin_score = (const float*)d_in[41];

  const int NS = in_sizes[0] / 3;
  const int NT = in_sizes[1] / 3;

  float* FB = (float*)d_ws;
  size_t off = 0;
  auto falloc = [&](size_t n){ float* p = FB + off; off += (n + 63) & ~size_t(63); return p; };
  float* Zx  = falloc(263169);
  float* Zt  = falloc(263169);
  float* Rr  = falloc(640);
  float* Cc  = falloc(640);
  float* wu  = falloc(640);
  float* wvg = falloc(640);
  float* cff = falloc(262144);
  u16* cf   = (u16*)falloc(65536);
  u16* qb   = (u16*)falloc(65536);
  u16* kb   = (u16*)falloc(65536);
  u16* vtb  = (u16*)falloc(65536);
  u16* msgb = (u16*)falloc(65536);
  u16* sfpb = (u16*)falloc(65536);
  u16* XA   = (u16*)falloc(2097152);   // [2][256][64][128] bf16
  u16* XB   = (u16*)falloc(2097152);
  u16* wsb  = (u16*)falloc(1269760);

  int* IB = (int*)(FB + off);
  size_t ioff = 0;
  auto ialloc = [&](size_t n){ int* p = IB + ioff; ioff += (n + 63) & ~size_t(63); return p; };
  int* bar  = ialloc(64);
  int* id_s = ialloc(NS);
  int* id_t = ialloc(NT);
  const int nbs = (NS + 255) / 256, nbt = (NT + 255) / 256;
  int* hist_s = ialloc((size_t)nbs * NODES);
  int* hist_t = ialloc((size_t)nbt * NODES);
  int* cnt_s = ialloc(NODES);
  int* cnt_t = ialloc(NODES);
  int* patch_s = ialloc(NODES*KP);
  int* patch_t = ialloc(NODES*KP);

  float* out0 = (float*)d_out;
  float* out_ls = out0 + ZDIM*ZDIM;
  float* out_gt = out_ls + (long)CC*65*65;

  u16* WcQ = wsb + 0;
  u16* WcK = wsb + 196608;
  u16* WcV = wsb + 393216;
  u16* WcM = wsb + 589824;
  u16* Wc1 = wsb + 786432;
  u16* Wc2 = wsb + 1572864;
  u16* Wfp = wsb + 1966080;
  u16* WlQ = wsb + 2031616;
  u16* WlK = wsb + 2080768;
  u16* WlV = wsb + 2129920;
  u16* WlM = wsb + 2179072;
  u16* Wl1 = wsb + 2228224;
  u16* Wl2 = wsb + 2424832;
  u16* Wlfp = wsb + 2523136;

  conv_weights<<<(2539520+255)/256, 256, 0, stream>>>(
      c_wq, c_wk, c_wv, c_wm, c_w1, c_w2, fp_w,
      l_wq, l_wk, l_wv, l_wm, l_w1, l_w2, lfp_w, wsb);

  // ---- NN + patches ----
  nn_kernel<<<nbs, 256, 0, stream>>>(src_pcd_c, NS, src_node_c, id_s);
  nn_kernel<<<nbt, 256, 0, stream>>>(tgt_pcd_c, NT, tgt_node_c, id_t);
  hist_kernel<<<nbs, 256, 0, stream>>>(id_s, NS, hist_s);
  hist_kernel<<<nbt, 256, 0, stream>>>(id_t, NT, hist_t);
  scan_kernel<<<1, 512, 0, stream>>>(hist_s, nbs, cnt_s);
  scan_kernel<<<1, 512, 0, stream>>>(hist_t, nbt, cnt_t);
  hipMemsetAsync(patch_s, 0, NODES*KP*sizeof(int), stream);
  hipMemsetAsync(patch_t, 0, NODES*KP*sizeof(int), stream);
  rank_kernel<<<nbs, 256, 0, stream>>>(id_s, NS, hist_s, patch_s);
  rank_kernel<<<nbt, 256, 0, stream>>>(id_t, NT, hist_t, patch_t);

  // ---- coarse transformer ----
  tr_in<<<1024, 256, 0, stream>>>(src_feats, tgt_feats, cf, cff);
  int crossL[3] = {0, 1, 0};
  for (int l = 0; l < 3; ++l){
    u16* wq = WcQ + (size_t)l*65536; u16* wk = WcK + (size_t)l*65536;
    u16* wv = WcV + (size_t)l*65536; u16* wm = WcM + (size_t)l*65536;
    u16* w1 = Wc1 + (size_t)l*262144; u16* w2 = Wc2 + (size_t)l*131072;
    const float* bq = c_bq + (size_t)l*256; const float* bk = c_bk + (size_t)l*256;
    const float* bv = c_bv + (size_t)l*256; const float* bm = c_bm + (size_t)l*256;
    const float* b1 = c_b1 + (size_t)l*512; const float* b2 = c_b2 + (size_t)l*256;
    coarse_qkv<<<48, 256, 0, stream>>>(cf, crossL[l], wq, wk, wv, bq, bk, bv, qb, kb, vtb);
    coarse_attn<<<64, 256, 0, stream>>>(qb, kb, vtb, msgb);
    coarse_ffn<<<16, 512, 0, stream>>>(msgb, cf, cff, wm, bm, w1, b1, w2, b2);
  }
  coarse_proj<<<16, 256, 0, stream>>>(cf, Wfp, fp_b, sfpb);
  coarse_scores<<<dim3(8,8), 256, 0, stream>>>(sfpb, sfpb + 131072, Zx);
  fill_border<<<3, 256, 0, stream>>>(Zx, bin_score);

  // ---- transport (persistent) ----
  transpose_k<<<dim3(17,17), 256, 0, stream>>>(Zx, Zt, ZDIM);
  hipMemsetAsync(bar, 0, 64*sizeof(int), stream);
  transport_persist<<<TPNB, 1024, 0, stream>>>(Zx, Zt, Rr, Cc, wu, wvg, out0, bar,
                                               logf(1024.0f));

  // ---- local transformer (ping-pong) ----
  gather_feats<<<CC, 256, 0, stream>>>(src_final, patch_s, node_corr, 0, XA);
  gather_feats<<<CC, 256, 0, stream>>>(tgt_final, patch_t, node_corr, 1, XA + 2097152);
  u16* Xi = XA; u16* Xo = XB;
  for (int l = 0; l < 3; ++l){
    u16* wq = WlQ + (size_t)l*16384; u16* wk = WlK + (size_t)l*16384;
    u16* wv = WlV + (size_t)l*16384; u16* wm = WlM + (size_t)l*16384;
    u16* w1 = Wl1 + (size_t)l*65536; u16* w2 = Wl2 + (size_t)l*32768;
    const float* bq = l_bq + (size_t)l*128; const float* bk = l_bk + (size_t)l*128;
    const float* bv = l_bv + (size_t)l*128; const float* bm = l_bm + (size_t)l*128;
    const float* b1 = l_b1 + (size_t)l*256; const float* b2 = l_b2 + (size_t)l*128;
    local_layer<<<512, 256, 0, stream>>>(Xi, Xo, crossL[l],
                                         wq,wk,wv,wm,w1,w2, bq,bk,bv,bm,b1,b2);
    u16* t = Xi; Xi = Xo; Xo = t;
  }
  // final features are in Xi after the swap
  sk_fused<<<CC, 1024, 0, stream>>>(Xi, Wlfp, lfp_b, node_corr, cnt_s, cnt_t, out_ls);

  // ---- GT ----
  gt_kernel<<<CC, 256, 0, stream>>>(src_raw, tgt_raw, rot, trans,
                                    patch_s, patch_t, node_corr, cnt_s, cnt_t, out_gt);

  (void)n_in; (void)out_size; (void)ws_size;
}

// Round 5
// 1389.234 us; speedup vs baseline: 1.3209x; 1.3209x over previous
//
#include <hip/hip_runtime.h>
#include <math.h>

static constexpr int NODES = 512;
static constexpr int CC    = 256;
static constexpr int KP    = 64;
static constexpr int ZDIM  = 513;

typedef unsigned short u16;
typedef short bf16x8 __attribute__((ext_vector_type(8)));
typedef float f32x4 __attribute__((ext_vector_type(4)));

__device__ __forceinline__ u16 f2b(float f){
  unsigned u = __float_as_uint(f);
  unsigned r = (u + 0x7FFF + ((u >> 16) & 1)) >> 16;
  return (u16)r;
}
__device__ __forceinline__ float b2f(u16 h){ return __uint_as_float(((unsigned)h) << 16); }
__device__ __forceinline__ f32x4 mfma16(bf16x8 a, bf16x8 b, f32x4 c){
  return __builtin_amdgcn_mfma_f32_16x16x32_bf16(a, b, c, 0, 0, 0);
}

// ======================= NN + patches (decision-exact) =======================
__global__ __launch_bounds__(256) void nn_kernel(const float* __restrict__ pts, int n,
                                                 const float* __restrict__ nodes,
                                                 int* __restrict__ out)
{
#pragma clang fp contract(off)
  __shared__ float nx[NODES], ny[NODES], nz[NODES], nn[NODES];
  for (int m = threadIdx.x; m < NODES; m += 256){
    float a = nodes[m*3+0], b = nodes[m*3+1], c = nodes[m*3+2];
    nx[m]=a; ny[m]=b; nz[m]=c;
    nn[m] = a*a + b*b + c*c;
  }
  __syncthreads();
  int i = blockIdx.x*256 + threadIdx.x;
  if (i >= n) return;
  float p0 = pts[i*3+0], p1 = pts[i*3+1], p2 = pts[i*3+2];
  float pp = p0*p0 + p1*p1 + p2*p2;
  float best = INFINITY; int bi = 0;
  for (int m = 0; m < NODES; ++m){
    float dot = fmaf(p2, nz[m], fmaf(p1, ny[m], p0*nx[m]));
    float d = (pp - 2.0f*dot) + nn[m];
    if (d < best){ best = d; bi = m; }
  }
  out[i] = bi;
}

__global__ __launch_bounds__(256) void hist_kernel(const int* __restrict__ id, int n,
                                                   int* __restrict__ hist)
{
  __shared__ int h[NODES];
  int t = threadIdx.x;
  h[t] = 0; h[t+256] = 0;
  __syncthreads();
  int i = blockIdx.x*256 + t;
  if (i < n) atomicAdd(&h[id[i]], 1);
  __syncthreads();
  hist[(long)blockIdx.x*NODES + t]       = h[t];
  hist[(long)blockIdx.x*NODES + t + 256] = h[t+256];
}

__global__ __launch_bounds__(512) void scan_kernel(int* __restrict__ hist, int nb,
                                                   int* __restrict__ counts)
{
  int m = threadIdx.x;
  int run = 0;
  for (int b = 0; b < nb; ++b){
    int t = hist[(long)b*NODES + m];
    hist[(long)b*NODES + m] = run;
    run += t;
  }
  counts[m] = run;
}

__global__ __launch_bounds__(256) void rank_kernel(const int* __restrict__ id, int n,
                                                   const int* __restrict__ hist,
                                                   int* __restrict__ patch)
{
  __shared__ int lid[256];
  int t = threadIdx.x;
  int i = blockIdx.x*256 + t;
  lid[t] = (i < n) ? id[i] : -1;
  __syncthreads();
  if (i >= n) return;
  int m = lid[t];
  int r = hist[(long)blockIdx.x*NODES + m];
  for (int q = 0; q < t; ++q) r += (lid[q] == m) ? 1 : 0;
  if (r < KP) patch[m*KP + r] = i;
}

// ======================= weight conversion =======================
__global__ __launch_bounds__(256) void conv_weights(
  const float* cwq, const float* cwk, const float* cwv, const float* cwm,
  const float* cw1, const float* cw2, const float* fpw,
  const float* lwq, const float* lwk, const float* lwv, const float* lwm,
  const float* lw1, const float* lw2, const float* lfp,
  u16* __restrict__ dst)
{
  int i = blockIdx.x*256 + threadIdx.x;
  if (i >= 2539520) return;
  const float* s; int off;
  if      (i <  196608){ s=cwq; off=0; }
  else if (i <  393216){ s=cwk; off=196608; }
  else if (i <  589824){ s=cwv; off=393216; }
  else if (i <  786432){ s=cwm; off=589824; }
  else if (i < 1572864){ s=cw1; off=786432; }
  else if (i < 1966080){ s=cw2; off=1572864; }
  else if (i < 2031616){ s=fpw; off=1966080; }
  else if (i < 2080768){ s=lwq; off=2031616; }
  else if (i < 2129920){ s=lwk; off=2080768; }
  else if (i < 2179072){ s=lwv; off=2129920; }
  else if (i < 2228224){ s=lwm; off=2179072; }
  else if (i < 2424832){ s=lw1; off=2228224; }
  else if (i < 2523136){ s=lw2; off=2424832; }
  else                 { s=lfp; off=2523136; }
  dst[i] = f2b(s[i - off]);
}

__global__ __launch_bounds__(256) void tr_in(const float* __restrict__ fs,
                                             const float* __restrict__ ft,
                                             u16* __restrict__ cf,
                                             float* __restrict__ cff)
{
  int i = blockIdx.x*256 + threadIdx.x;
  if (i >= 262144) return;
  int side = i >> 17; int r = i & 131071; int d = r >> 9; int n = r & 511;
  float v = (side ? ft : fs)[r];
  long o = ((long)side*512 + n)*256 + d;
  cf[o] = f2b(v);
  cff[o] = v;
}

// ======================= coarse transformer (bf16 MFMA, [n][d]) =======================
// qkv: grid 24*nsides: z -> side=side0+z/24, rem=z%24, proj=rem>>3, slice=rem&7
__global__ __launch_bounds__(256) void coarse_qkv(
    const u16* __restrict__ cf, int cross, int side0,
    const u16* __restrict__ Wq, const u16* __restrict__ Wk, const u16* __restrict__ Wv,
    const float* __restrict__ bq, const float* __restrict__ bk, const float* __restrict__ bv,
    u16* __restrict__ qb, u16* __restrict__ kb, u16* __restrict__ vtb)
{
  int z = blockIdx.x;
  int side = side0 + z/24, rem = z%24, proj = rem >> 3, slice = rem & 7;
  const u16* x = cf + (long)side*131072;
  const u16* s = cross ? cf + (long)(1-side)*131072 : x;
  const u16* in = (proj == 0) ? x : s;
  const u16* W  = (proj==0)?Wq:(proj==1)?Wk:Wv;
  const float* bi = (proj==0)?bq:(proj==1)?bk:bv;
  int n0 = slice << 6;
  int wv_ = threadIdx.x >> 6, L = threadIdx.x & 63, lr = L & 15, lk = L >> 4;
  const u16* inb = in + (long)(n0 + lr)*256 + 8*lk;
  for (int oi = 0; oi < 4; ++oi){
    int o0 = (wv_*4 + oi) << 4;
    const u16* wrow = W + (long)(o0 + lr)*256 + 8*lk;
    f32x4 acc[4] = {};
#pragma unroll
    for (int ks = 0; ks < 8; ++ks){
      bf16x8 b = *(const bf16x8*)(wrow + ks*32);
#pragma unroll
      for (int a = 0; a < 4; ++a){
        bf16x8 av = *(const bf16x8*)(inb + a*16*256 + ks*32);
        acc[a] = mfma16(av, b, acc[a]);
      }
    }
    int col = o0 + lr;
    float bvv = bi[col];
    if (proj < 2){
      u16* o = (proj==0 ? qb : kb) + ((long)side*512 + n0)*256 + col;
#pragma unroll
      for (int a = 0; a < 4; ++a)
#pragma unroll
        for (int q_ = 0; q_ < 4; ++q_)
          o[(long)(a*16 + lk*4 + q_)*256] = f2b(acc[a][q_] + bvv);
    } else {
      u16* o = vtb + ((long)side*256 + col)*512 + n0;
#pragma unroll
      for (int a = 0; a < 4; ++a)
#pragma unroll
        for (int q_ = 0; q_ < 4; ++q_)
          o[a*16 + lk*4 + q_] = f2b(acc[a][q_] + bvv);
    }
  }
}

// attn: grid 32*nsides: z -> side=side0+z/32, rem: head=(rem>>3), qs=rem&7
__global__ __launch_bounds__(256) void coarse_attn(
    const u16* __restrict__ qb, const u16* __restrict__ kb,
    const u16* __restrict__ vtb, u16* __restrict__ msgb, int side0)
{
  __shared__ u16 P[64][512];
  __shared__ float rmx[64][4], rsm[64][4];
  int z = blockIdx.x;
  int side = side0 + (z >> 5); int rem = z & 31;
  int head = rem >> 3, qs = rem & 7;
  int wv_ = threadIdx.x >> 6, L = threadIdx.x & 63, lr = L & 15, lk = L >> 4;
  const u16* q = qb + ((long)side*512 + qs*64)*256 + head*64;
  const u16* k = kb + (long)side*512*256 + head*64;
  const u16* vt = vtb + ((long)side*256 + head*64)*512;

  bf16x8 af[4][2];
#pragma unroll
  for (int a = 0; a < 4; ++a)
#pragma unroll
    for (int ks = 0; ks < 2; ++ks)
      af[a][ks] = *(const bf16x8*)(q + (long)(a*16 + lr)*256 + ks*32 + 8*lk);

  f32x4 sc[4][8] = {};
  for (int b = 0; b < 8; ++b){
    const u16* krow = k + (long)(wv_*128 + b*16 + lr)*256 + 8*lk;
#pragma unroll
    for (int ks = 0; ks < 2; ++ks){
      bf16x8 bf = *(const bf16x8*)(krow + ks*32);
#pragma unroll
      for (int a = 0; a < 4; ++a)
        sc[a][b] = mfma16(af[a][ks], bf, sc[a][b]);
    }
  }
  const float SC = 0.125f; // 1/sqrt(64)
#pragma unroll
  for (int a = 0; a < 4; ++a)
#pragma unroll
    for (int q_ = 0; q_ < 4; ++q_){
      float m = sc[a][0][q_];
#pragma unroll
      for (int b = 1; b < 8; ++b) m = fmaxf(m, sc[a][b][q_]);
      m = fmaxf(m, __shfl_xor(m, 1)); m = fmaxf(m, __shfl_xor(m, 2));
      m = fmaxf(m, __shfl_xor(m, 4)); m = fmaxf(m, __shfl_xor(m, 8));
      if (lr == 0) rmx[a*16 + lk*4 + q_][wv_] = m;
    }
  __syncthreads();
#pragma unroll
  for (int a = 0; a < 4; ++a)
#pragma unroll
    for (int q_ = 0; q_ < 4; ++q_){
      int row = a*16 + lk*4 + q_;
      float m = fmaxf(fmaxf(rmx[row][0], rmx[row][1]), fmaxf(rmx[row][2], rmx[row][3]));
      float s = 0.f;
#pragma unroll
      for (int b = 0; b < 8; ++b){
        float e = __expf((sc[a][b][q_] - m)*SC);
        sc[a][b][q_] = e; s += e;
      }
      s += __shfl_xor(s,1); s += __shfl_xor(s,2); s += __shfl_xor(s,4); s += __shfl_xor(s,8);
      if (lr == 0) rsm[row][wv_] = s;
    }
  __syncthreads();
#pragma unroll
  for (int a = 0; a < 4; ++a)
#pragma unroll
    for (int q_ = 0; q_ < 4; ++q_){
      int row = a*16 + lk*4 + q_;
      float inv = 1.f / (rsm[row][0]+rsm[row][1]+rsm[row][2]+rsm[row][3]);
#pragma unroll
      for (int b = 0; b < 8; ++b)
        P[row][wv_*128 + b*16 + lr] = f2b(sc[a][b][q_] * inv);
    }
  __syncthreads();
  f32x4 mv[4] = {};
  for (int ks = 0; ks < 16; ++ks){
    bf16x8 bf = *(const bf16x8*)(vt + (long)(wv_*16 + lr)*512 + ks*32 + 8*lk);
#pragma unroll
    for (int a = 0; a < 4; ++a){
      bf16x8 av = *(const bf16x8*)(&P[a*16 + lr][ks*32 + 8*lk]);
      mv[a] = mfma16(av, bf, mv[a]);
    }
  }
  u16* o = msgb + ((long)side*512 + qs*64)*256 + head*64 + wv_*16 + lr;
#pragma unroll
  for (int a = 0; a < 4; ++a)
#pragma unroll
    for (int q_ = 0; q_ < 4; ++q_)
      o[(long)(a*16 + lk*4 + q_)*256] = f2b(mv[a][q_]);
}

// ffn: grid 8*nsides, 512 threads: z -> side=side0+z/8, slice=z&7
__global__ __launch_bounds__(512) void coarse_ffn(
    const u16* __restrict__ msgb, u16* __restrict__ cf, float* __restrict__ cff,
    const u16* __restrict__ Wm, const float* __restrict__ bm,
    const u16* __restrict__ W1, const float* __restrict__ b1,
    const u16* __restrict__ W2, const float* __restrict__ b2, int side0)
{
  __shared__ u16 m2[64*256];
  __shared__ u16 h1[64*512];
  int z = blockIdx.x;
  int side = side0 + (z >> 3), slice = z & 7;
  int wv_ = threadIdx.x >> 6, L = threadIdx.x & 63, lr = L & 15, lk = L >> 4;
  const u16* msg = msgb + ((long)side*512 + slice*64)*256;
  u16* x = cf + ((long)side*512 + slice*64)*256;
  float* xf = cff + ((long)side*512 + slice*64)*256;
  for (int oi = 0; oi < 2; ++oi){
    int o0 = (wv_*2 + oi) << 4;
    f32x4 acc[4] = {};
    const u16* wrow = Wm + (long)(o0+lr)*256 + 8*lk;
#pragma unroll
    for (int ks = 0; ks < 8; ++ks){
      bf16x8 b = *(const bf16x8*)(wrow + ks*32);
#pragma unroll
      for (int a = 0; a < 4; ++a){
        bf16x8 av = *(const bf16x8*)(msg + (long)(a*16+lr)*256 + ks*32 + 8*lk);
        acc[a] = mfma16(av, b, acc[a]);
      }
    }
    int col = o0 + lr; float bb = bm[col];
#pragma unroll
    for (int a = 0; a < 4; ++a)
#pragma unroll
      for (int q_ = 0; q_ < 4; ++q_)
        m2[(a*16+lk*4+q_)*256 + col] = f2b(acc[a][q_] + bb);
  }
  __syncthreads();
  for (int oi = 0; oi < 4; ++oi){
    int o0 = (wv_*4 + oi) << 4;
    f32x4 acc[4] = {};
    const u16* wrow = W1 + (long)(o0+lr)*512 + 8*lk;
#pragma unroll
    for (int ks = 0; ks < 16; ++ks){
      int kk = ks*32;
      bf16x8 b = *(const bf16x8*)(wrow + kk);
#pragma unroll
      for (int a = 0; a < 4; ++a){
        bf16x8 av;
        if (kk < 256) av = *(const bf16x8*)(x + (long)(a*16+lr)*256 + kk + 8*lk);
        else          av = *(const bf16x8*)(&m2[(a*16+lr)*256 + kk - 256 + 8*lk]);
        acc[a] = mfma16(av, b, acc[a]);
      }
    }
    int col = o0 + lr; float bb = b1[col];
#pragma unroll
    for (int a = 0; a < 4; ++a)
#pragma unroll
      for (int q_ = 0; q_ < 4; ++q_)
        h1[(a*16+lk*4+q_)*512 + col] = f2b(fmaxf(acc[a][q_] + bb, 0.f));
  }
  __syncthreads();
  for (int oi = 0; oi < 2; ++oi){
    int o0 = (wv_*2 + oi) << 4;
    f32x4 acc[4] = {};
    const u16* wrow = W2 + (long)(o0+lr)*512 + 8*lk;
#pragma unroll
    for (int ks = 0; ks < 16; ++ks){
      bf16x8 b = *(const bf16x8*)(wrow + ks*32);
#pragma unroll
      for (int a = 0; a < 4; ++a){
        bf16x8 av = *(const bf16x8*)(&h1[(a*16+lr)*512 + ks*32 + 8*lk]);
        acc[a] = mfma16(av, b, acc[a]);
      }
    }
    int col = o0 + lr; float bb = b2[col];
#pragma unroll
    for (int a = 0; a < 4; ++a)
#pragma unroll
      for (int q_ = 0; q_ < 4; ++q_){
        long idx = (long)(a*16+lk*4+q_)*256 + col;
        float v = acc[a][q_] + bb + xf[idx];
        xf[idx] = v;
        x[idx] = f2b(v);
      }
  }
}

__global__ __launch_bounds__(256) void coarse_proj(
    const u16* __restrict__ cf, const u16* __restrict__ W,
    const float* __restrict__ bias, u16* __restrict__ out)
{
  int z = blockIdx.x;
  int side = z >> 3, slice = z & 7;
  const u16* in = cf + (long)side*131072;
  u16* o = out + (long)side*131072;
  int n0 = slice << 6;
  int wv_ = threadIdx.x >> 6, L = threadIdx.x & 63, lr = L & 15, lk = L >> 4;
  const u16* inb = in + (long)(n0 + lr)*256 + 8*lk;
  for (int oi = 0; oi < 4; ++oi){
    int o0 = (wv_*4 + oi) << 4;
    const u16* wrow = W + (long)(o0 + lr)*256 + 8*lk;
    f32x4 acc[4] = {};
#pragma unroll
    for (int ks = 0; ks < 8; ++ks){
      bf16x8 b = *(const bf16x8*)(wrow + ks*32);
#pragma unroll
      for (int a = 0; a < 4; ++a){
        bf16x8 av = *(const bf16x8*)(inb + a*16*256 + ks*32);
        acc[a] = mfma16(av, b, acc[a]);
      }
    }
    int col = o0 + lr; float bb = bias[col];
#pragma unroll
    for (int a = 0; a < 4; ++a)
#pragma unroll
      for (int q_ = 0; q_ < 4; ++q_)
        o[(long)(n0 + a*16 + lk*4 + q_)*256 + col] = f2b(acc[a][q_] + bb);
  }
}

__global__ __launch_bounds__(256) void coarse_scores(
    const u16* __restrict__ sfp, const u16* __restrict__ tfp, float* __restrict__ Z)
{
  int n0 = blockIdx.y << 6, m0 = blockIdx.x << 6;
  int wv_ = threadIdx.x >> 6, L = threadIdx.x & 63, lr = L & 15, lk = L >> 4;
  f32x4 acc[4] = {};
  const u16* arow = sfp + (long)(n0 + lr)*256 + 8*lk;
  const u16* brow = tfp + (long)(m0 + wv_*16 + lr)*256 + 8*lk;
#pragma unroll
  for (int ks = 0; ks < 8; ++ks){
    bf16x8 b = *(const bf16x8*)(brow + ks*32);
#pragma unroll
    for (int a = 0; a < 4; ++a){
      bf16x8 av = *(const bf16x8*)(arow + a*16*256 + ks*32);
      acc[a] = mfma16(av, b, acc[a]);
    }
  }
  int col = m0 + wv_*16 + lr;
#pragma unroll
  for (int a = 0; a < 4; ++a)
#pragma unroll
    for (int q_ = 0; q_ < 4; ++q_)
      Z[(long)(n0 + a*16 + lk*4 + q_)*513 + col] = acc[a][q_]*0.0625f;
}

// ======================= transport =======================
__global__ __launch_bounds__(256) void fill_border(float* Z, const float* __restrict__ alpha)
{
  int i = blockIdx.x*256 + threadIdx.x;
  if (i < ZDIM){
    float a = alpha[0];
    Z[(long)i*ZDIM + (ZDIM-1)] = a;
    Z[(long)(ZDIM-1)*ZDIM + i] = a;
  }
}

__global__ __launch_bounds__(256) void transpose_k(const float* __restrict__ A,
                                                   float* __restrict__ B, int n)
{
  __shared__ float t[32][33];
  int bx = blockIdx.x*32, by = blockIdx.y*32;
  int lx = threadIdx.x & 31, ly0 = threadIdx.x >> 5;
  for (int dy = 0; dy < 32; dy += 8){
    int x = bx + lx, y = by + ly0 + dy;
    if (x < n && y < n) t[ly0+dy][lx] = A[(long)y*n + x];
  }
  __syncthreads();
  for (int dy = 0; dy < 32; dy += 8){
    int x = by + lx, y = bx + ly0 + dy;
    if (x < n && y < n) B[(long)y*n + x] = t[lx][ly0+dy];
  }
}

// persistent exp-domain sinkhorn: 16 blocks, LDS-resident slices.
// ALL cross-block data via RELAXED agent-scope atomics (no fences, no cache flushes).
// Barrier: per-phase arrival counter; __syncthreads() drains vmcnt first.
static constexpr int TPNB = 16;
static constexpr int TPROWS = 33;

__device__ __forceinline__ float aload(const float* p){
  return __hip_atomic_load(p, __ATOMIC_RELAXED, __HIP_MEMORY_SCOPE_AGENT);
}
__device__ __forceinline__ void astore(float* p, float v){
  __hip_atomic_store(p, v, __ATOMIC_RELAXED, __HIP_MEMORY_SCOPE_AGENT);
}

__device__ __forceinline__ void gbar2(int* cnt, int ph){
  __syncthreads();   // drains vmcnt for all waves -> data atomics complete
  if (threadIdx.x == 0){
    __hip_atomic_fetch_add(&cnt[ph], 1, __ATOMIC_RELAXED, __HIP_MEMORY_SCOPE_AGENT);
    while (__hip_atomic_load(&cnt[ph], __ATOMIC_RELAXED, __HIP_MEMORY_SCOPE_AGENT) < TPNB) {}
  }
  __syncthreads();
}

__global__ __launch_bounds__(1024) void transport_persist(
    const float* __restrict__ Z, const float* __restrict__ Zt,
    float* __restrict__ Rr, float* __restrict__ Cc,
    float* __restrict__ wu, float* __restrict__ wvv,
    float* __restrict__ out, int* cnt, float outadd)
{
  __shared__ float A[TPROWS*513];
  __shared__ float B[TPROWS*513];
  __shared__ float RrL[513], CcL[513], M[513];
  __shared__ float rown[TPROWS], cown[TPROWS], uown[TPROWS];
  int bid = blockIdx.x, tid = threadIdx.x;
  int wv_ = tid >> 6, lane = tid & 63;
  int r0 = bid * TPROWS;
  int nr = 513 - r0; if (nr > TPROWS) nr = TPROWS;

  for (int i = wv_; i < nr; i += 16){
    const float* zr  = Z  + (long)(r0+i)*513;
    const float* ztr = Zt + (long)(r0+i)*513;
    for (int j = lane; j < 513; j += 64){ A[i*513+j] = zr[j]; B[i*513+j] = ztr[j]; }
  }
  __syncthreads();
  // rowmax of Z rows
  for (int i = wv_; i < nr; i += 16){
    float m = -INFINITY;
    for (int j = lane; j < 513; j += 64) m = fmaxf(m, A[i*513+j]);
    for (int o = 32; o; o >>= 1) m = fmaxf(m, __shfl_xor(m, o));
    if (lane == 0){ rown[i] = m; astore(&Rr[r0+i], m); }
  }
  gbar2(cnt, 1);
  for (int j = tid; j < 513; j += 1024) RrL[j] = aload(&Rr[j]);
  __syncthreads();
  // colmax: Cc[r] = max_j (Zt[r][j] - Rr[j])
  for (int i = wv_; i < nr; i += 16){
    float m = -INFINITY;
    for (int j = lane; j < 513; j += 64) m = fmaxf(m, B[i*513+j] - RrL[j]);
    for (int o = 32; o; o >>= 1) m = fmaxf(m, __shfl_xor(m, o));
    if (lane == 0){ cown[i] = m; astore(&Cc[r0+i], m); }
  }
  gbar2(cnt, 2);
  for (int j = tid; j < 513; j += 1024) CcL[j] = aload(&Cc[j]);
  __syncthreads();
  // exponentiate in place
  for (int i = wv_; i < nr; i += 16){
    float ro = rown[i], co = cown[i];
    for (int j = lane; j < 513; j += 64){
      A[i*513+j] = __expf(A[i*513+j] - ro - CcL[j]);
      B[i*513+j] = __expf(B[i*513+j] - co - RrL[j]);
    }
  }
  __syncthreads();
  const float EBM = 1.0f/1024.0f, EBL = 0.5f;
  int ph = 2;
  for (int it = 0; it < 50; ++it){
    // u phase (M holds prev v-factors; it==0 means v=1)
    for (int i = wv_; i < nr; i += 16){
      float s = 0.f;
      if (it == 0){ for (int j = lane; j < 513; j += 64) s += A[i*513+j]; }
      else        { for (int j = lane; j < 513; j += 64) s = fmaf(A[i*513+j], M[j], s); }
      for (int o = 32; o; o >>= 1) s += __shfl_xor(s, o);
      if (lane == 0){
        int r = r0+i; float u = ((r < 512) ? EBM : EBL) / s;
        uown[i] = u; astore(&wu[r], u);
      }
    }
    gbar2(cnt, ++ph);
    for (int j = tid; j < 513; j += 1024) M[j] = aload(&wu[j]);
    __syncthreads();
    // v phase
    for (int i = wv_; i < nr; i += 16){
      float s = 0.f;
      for (int j = lane; j < 513; j += 64) s = fmaf(B[i*513+j], M[j], s);
      for (int o = 32; o; o >>= 1) s += __shfl_xor(s, o);
      if (lane == 0){
        int r = r0+i;
        astore(&wvv[r], ((r < 512) ? EBM : EBL) / s);
      }
    }
    gbar2(cnt, ++ph);
    for (int j = tid; j < 513; j += 1024) M[j] = aload(&wvv[j]);
    __syncthreads();
  }
  // epilogue: out = Z + (log u - R) + (log v - C) + log(m+n)
  for (int j = tid; j < 513; j += 1024) M[j] = __logf(M[j]) - CcL[j];
  __syncthreads();
  for (int i = wv_; i < nr; i += 16){
    int r = r0 + i;
    float uu = __logf(uown[i]) - rown[i];
    const float* zr = Z + (long)r*513;
    float* orow = out + (long)r*513;
    for (int j = lane; j < 513; j += 64) orow[j] = zr[j] + uu + M[j] + outadd;
  }
}

// ======================= local gather (bf16 [c][n][d]) =======================
__global__ __launch_bounds__(256) void gather_feats(const float* __restrict__ F,
                                                    const int* __restrict__ patch,
                                                    const int* __restrict__ corr,
                                                    int side, u16* __restrict__ out)
{
  int c = blockIdx.x;
  __shared__ int sel[KP];
  int tid = threadIdx.x;
  if (tid < KP){
    int node = corr[c*2 + side];
    sel[tid] = patch[node*KP + tid];
  }
  __syncthreads();
  for (int e = tid; e < KP*128; e += 256){
    int n = e >> 7, d = e & 127;
    out[((long)c*KP + n)*128 + d] = f2b(F[(long)sel[n]*128 + d]);
  }
}

// ======================= fused local transformer layer (in-place, sequential-cross) =======================
__global__ __launch_bounds__(256) void local_layer(
    u16* __restrict__ X, int cross, int side0,
    const u16* __restrict__ Wq, const u16* __restrict__ Wk,
    const u16* __restrict__ Wv, const u16* __restrict__ Wm,
    const u16* __restrict__ W1, const u16* __restrict__ W2,
    const float* __restrict__ bq, const float* __restrict__ bk,
    const float* __restrict__ bv, const float* __restrict__ bm,
    const float* __restrict__ b1, const float* __restrict__ b2)
{
  __shared__ u16 pool[32768];
  int z = blockIdx.x;
  int side = side0 + (z >> 8), c = z & 255;
  u16* x = X + ((long)side*256 + c)*8192;
  const u16* s = X + ((long)(cross ? 1-side : side)*256 + c)*8192;
  int wv_ = threadIdx.x >> 6, L = threadIdx.x & 63, lr = L & 15, lk = L >> 4;
  u16* qS = pool; u16* kS = pool + 8192; u16* vT = pool + 16384; u16* msgS = pool + 24576;

#pragma unroll
  for (int proj = 0; proj < 3; ++proj){
    const u16* in = proj ? s : x;
    const u16* W = proj==0?Wq:proj==1?Wk:Wv;
    const float* bi = proj==0?bq:proj==1?bk:bv;
#pragma unroll
    for (int oi = 0; oi < 2; ++oi){
      int o0 = (wv_ + oi*4) << 4;
      f32x4 acc[4] = {};
      const u16* wrow = W + (long)(o0+lr)*128 + 8*lk;
      const u16* inr = in + (long)lr*128 + 8*lk;
#pragma unroll
      for (int ks = 0; ks < 4; ++ks){
        bf16x8 b = *(const bf16x8*)(wrow + ks*32);
#pragma unroll
        for (int a = 0; a < 4; ++a){
          bf16x8 av = *(const bf16x8*)(inr + a*16*128 + ks*32);
          acc[a] = mfma16(av, b, acc[a]);
        }
      }
      int col = o0 + lr; float bb = bi[col];
      if (proj < 2){
        u16* dst = (proj==0 ? qS : kS);
#pragma unroll
        for (int a = 0; a < 4; ++a)
#pragma unroll
          for (int q_ = 0; q_ < 4; ++q_)
            dst[(a*16 + lk*4 + q_)*128 + col] = f2b(acc[a][q_] + bb);
      } else {
#pragma unroll
        for (int a = 0; a < 4; ++a)
#pragma unroll
          for (int q_ = 0; q_ < 4; ++q_)
            vT[col*64 + a*16 + lk*4 + q_] = f2b(acc[a][q_] + bb);
      }
    }
  }
  __syncthreads();
  int h = wv_;
  bf16x8 qf[4], kf[4];
#pragma unroll
  for (int a = 0; a < 4; ++a){
    qf[a] = *(const bf16x8*)(&qS[(a*16+lr)*128 + h*32 + 8*lk]);
    kf[a] = *(const bf16x8*)(&kS[(a*16+lr)*128 + h*32 + 8*lk]);
  }
  f32x4 sc[4][4] = {};
#pragma unroll
  for (int b = 0; b < 4; ++b)
#pragma unroll
    for (int a = 0; a < 4; ++a)
      sc[a][b] = mfma16(qf[a], kf[b], sc[a][b]);
  const float SCs = 0.17677669529663687f;
  float invs[4][4];
#pragma unroll
  for (int a = 0; a < 4; ++a)
#pragma unroll
    for (int q_ = 0; q_ < 4; ++q_){
      float m = sc[a][0][q_];
#pragma unroll
      for (int b = 1; b < 4; ++b) m = fmaxf(m, sc[a][b][q_]);
      m = fmaxf(m, __shfl_xor(m, 1)); m = fmaxf(m, __shfl_xor(m, 2));
      m = fmaxf(m, __shfl_xor(m, 4)); m = fmaxf(m, __shfl_xor(m, 8));
      float ss = 0.f;
#pragma unroll
      for (int b = 0; b < 4; ++b){
        float e = __expf((sc[a][b][q_] - m)*SCs);
        sc[a][b][q_] = e; ss += e;
      }
      ss += __shfl_xor(ss,1); ss += __shfl_xor(ss,2); ss += __shfl_xor(ss,4); ss += __shfl_xor(ss,8);
      invs[a][q_] = 1.f/ss;
    }
  __syncthreads();
  u16* P = pool + h*4096;
#pragma unroll
  for (int a = 0; a < 4; ++a)
#pragma unroll
    for (int q_ = 0; q_ < 4; ++q_)
#pragma unroll
      for (int b = 0; b < 4; ++b)
        P[(a*16 + lk*4 + q_)*64 + b*16 + lr] = f2b(sc[a][q_*0 + b][q_] * invs[a][q_]);
  f32x4 mv[4][2] = {};
#pragma unroll
  for (int ks = 0; ks < 2; ++ks)
#pragma unroll
    for (int bt = 0; bt < 2; ++bt){
      bf16x8 bf = *(const bf16x8*)(&vT[(h*32 + bt*16 + lr)*64 + ks*32 + 8*lk]);
#pragma unroll
      for (int a = 0; a < 4; ++a){
        bf16x8 av = *(const bf16x8*)(&P[(a*16+lr)*64 + ks*32 + 8*lk]);
        mv[a][bt] = mfma16(av, bf, mv[a][bt]);
      }
    }
#pragma unroll
  for (int a = 0; a < 4; ++a)
#pragma unroll
    for (int bt = 0; bt < 2; ++bt)
#pragma unroll
      for (int q_ = 0; q_ < 4; ++q_)
        msgS[(a*16 + lk*4 + q_)*128 + h*32 + bt*16 + lr] = f2b(mv[a][bt][q_]);
  __syncthreads();
  u16* m2 = pool;
#pragma unroll
  for (int oi = 0; oi < 2; ++oi){
    int o0 = (wv_ + oi*4) << 4;
    f32x4 acc[4] = {};
    const u16* wrow = Wm + (long)(o0+lr)*128 + 8*lk;
#pragma unroll
    for (int ks = 0; ks < 4; ++ks){
      bf16x8 b = *(const bf16x8*)(wrow + ks*32);
#pragma unroll
      for (int a = 0; a < 4; ++a){
        bf16x8 av = *(const bf16x8*)(&msgS[(a*16+lr)*128 + ks*32 + 8*lk]);
        acc[a] = mfma16(av, b, acc[a]);
      }
    }
    int col = o0+lr; float bb = bm[col];
#pragma unroll
    for (int a = 0; a < 4; ++a)
#pragma unroll
      for (int q_ = 0; q_ < 4; ++q_)
        m2[(a*16+lk*4+q_)*128 + col] = f2b(acc[a][q_] + bb);
  }
  __syncthreads();
  u16* h1 = pool + 8192;
#pragma unroll
  for (int oi = 0; oi < 4; ++oi){
    int o0 = (wv_*4 + oi) << 4;
    f32x4 acc[4] = {};
    const u16* wrow = W1 + (long)(o0+lr)*256 + 8*lk;
#pragma unroll
    for (int ks = 0; ks < 8; ++ks){
      int kk = ks*32;
      bf16x8 b = *(const bf16x8*)(wrow + kk);
#pragma unroll
      for (int a = 0; a < 4; ++a){
        bf16x8 av;
        if (kk < 128) av = *(const bf16x8*)(x + (long)(a*16+lr)*128 + kk + 8*lk);
        else          av = *(const bf16x8*)(&m2[(a*16+lr)*128 + kk - 128 + 8*lk]);
        acc[a] = mfma16(av, b, acc[a]);
      }
    }
    int col = o0+lr; float bb = b1[col];
#pragma unroll
    for (int a = 0; a < 4; ++a)
#pragma unroll
      for (int q_ = 0; q_ < 4; ++q_)
        h1[(a*16+lk*4+q_)*256 + col] = f2b(fmaxf(acc[a][q_] + bb, 0.f));
  }
  __syncthreads();
#pragma unroll
  for (int oi = 0; oi < 2; ++oi){
    int o0 = (wv_ + oi*4) << 4;
    f32x4 acc[4] = {};
    const u16* wrow = W2 + (long)(o0+lr)*256 + 8*lk;
#pragma unroll
    for (int ks = 0; ks < 8; ++ks){
      bf16x8 b = *(const bf16x8*)(wrow + ks*32);
#pragma unroll
      for (int a = 0; a < 4; ++a){
        bf16x8 av = *(const bf16x8*)(&h1[(a*16+lr)*256 + ks*32 + 8*lk]);
        acc[a] = mfma16(av, b, acc[a]);
      }
    }
    int col = o0+lr; float bb = b2[col];
#pragma unroll
    for (int a = 0; a < 4; ++a)
#pragma unroll
      for (int q_ = 0; q_ < 4; ++q_){
        int ri = (a*16+lk*4+q_)*128 + col;
        x[ri] = f2b(acc[a][q_] + bb + b2f(x[ri]));
      }
  }
}

// ======================= fused lfp + scores + multiplicative sinkhorn =======================
__global__ __launch_bounds__(1024) void sk_fused(
    const u16* __restrict__ X, const u16* __restrict__ lfpW, const float* __restrict__ lfpB,
    const int* __restrict__ corr, const int* __restrict__ cnt_s,
    const int* __restrict__ cnt_t, float* __restrict__ out)
{
  __shared__ u16 sptp[16384];
  __shared__ float LA[65][66];
  __shared__ float ET[65*66];
  __shared__ float uvec[65], vvec[65], u0s[65], Ul[65], Vl[65];
  float* E = (float*)sptp;
  u16* sp = sptp; u16* tp = sptp + 8192;
  int cpat = blockIdx.x;
  int tid = threadIdx.x;
  int wv_ = tid >> 6, L = tid & 63, lr = L & 15, lk = L >> 4;

  {
    const u16* in = X + ((long)((wv_>>3)*256 + cpat))*8192;
    u16* dst = (wv_ < 8) ? sp : tp;
    int o0 = (wv_ & 7) << 4;
    f32x4 acc[4] = {};
    const u16* wrow = lfpW + (long)(o0+lr)*128 + 8*lk;
    const u16* inr = in + (long)lr*128 + 8*lk;
#pragma unroll
    for (int ks = 0; ks < 4; ++ks){
      bf16x8 b = *(const bf16x8*)(wrow + ks*32);
#pragma unroll
      for (int a = 0; a < 4; ++a){
        bf16x8 av = *(const bf16x8*)(inr + a*16*128 + ks*32);
        acc[a] = mfma16(av, b, acc[a]);
      }
    }
    int col = o0 + lr; float bb = lfpB[col];
#pragma unroll
    for (int a = 0; a < 4; ++a)
#pragma unroll
      for (int q_ = 0; q_ < 4; ++q_)
        dst[(a*16 + lk*4 + q_)*128 + col] = f2b(acc[a][q_] + bb);
  }
  __syncthreads();
  int cs = cnt_s[corr[cpat*2]], ct = cnt_t[corr[cpat*2+1]];
  {
    int mt = wv_ >> 2, nt = wv_ & 3;
    f32x4 acc = {};
    const u16* arow = sp + (mt*16 + lr)*128 + 8*lk;
    const u16* brow = tp + (nt*16 + lr)*128 + 8*lk;
#pragma unroll
    for (int ks = 0; ks < 4; ++ks){
      bf16x8 a = *(const bf16x8*)(arow + ks*32);
      bf16x8 b = *(const bf16x8*)(brow + ks*32);
      acc = mfma16(a, b, acc);
    }
    const float SCS = 0.08838834764831845f;
#pragma unroll
    for (int q_ = 0; q_ < 4; ++q_){
      int row = mt*16 + lk*4 + q_;
      int col = nt*16 + lr;
      float v = acc[q_] * SCS;
      if (row >= cs || col >= ct) v = -1000000.0f;
      LA[row][col] = v;
    }
  }
  if (tid < 65){ LA[64][tid] = 0.f; LA[tid][64] = 0.f; uvec[tid] = 1.f; vvec[tid] = 1.f; }
  __syncthreads();
  int g = tid >> 4, sub = tid & 15;
  {
    float mx = -INFINITY;
    for (int j = sub; j < 65; j += 16) mx = fmaxf(mx, LA[g][j]);
    mx = fmaxf(mx, __shfl_xor(mx, 1)); mx = fmaxf(mx, __shfl_xor(mx, 2));
    mx = fmaxf(mx, __shfl_xor(mx, 4)); mx = fmaxf(mx, __shfl_xor(mx, 8));
    float s = 0.f;
    for (int j = sub; j < 65; j += 16) s += __expf(LA[g][j] - mx);
    s += __shfl_xor(s,1); s += __shfl_xor(s,2); s += __shfl_xor(s,4); s += __shfl_xor(s,8);
    float u0 = mx + __logf(s);
    if (sub == 0) u0s[g] = u0;
    for (int j = sub; j < 65; j += 16){
      float e = __expf(LA[g][j] - u0);
      E[g*66 + j] = e;
      ET[j*66 + g] = e;
    }
  }
  if (tid < 65){
    E[64*66 + tid] = 1.f;
    ET[tid*66 + 64] = 1.f;
    if (tid == 64) u0s[64] = 0.f;
  }
  __syncthreads();
  for (int it = 0; it < 50; ++it){
    {
      float s = 0.f;
      for (int r = sub; r < 65; r += 16) s = fmaf(ET[g*66 + r], uvec[r], s);
      s += __shfl_xor(s,1); s += __shfl_xor(s,2); s += __shfl_xor(s,4); s += __shfl_xor(s,8);
      if (sub == 0) vvec[g] = 1.f / s;
    }
    __syncthreads();
    if (it == 49) break;
    {
      float s = 0.f;
      for (int j = sub; j < 65; j += 16) s = fmaf(E[g*66 + j], vvec[j], s);
      s += __shfl_xor(s,1); s += __shfl_xor(s,2); s += __shfl_xor(s,4); s += __shfl_xor(s,8);
      if (sub == 0) uvec[g] = 1.f / s;
    }
    __syncthreads();
  }
  __syncthreads();
  if (tid < 65){ Ul[tid] = u0s[tid] - __logf(uvec[tid]); Vl[tid] = -__logf(vvec[tid]); }
  __syncthreads();
  for (int e = tid; e < 4225; e += 1024){
    int r = e / 65, c2 = e % 65;
    out[(long)cpat*4225 + e] = LA[r][c2] - Ul[r] - Vl[c2];
  }
}

// ======================= GT (decision-exact) =======================
__global__ __launch_bounds__(256) void gt_kernel(const float* __restrict__ sraw,
                                                 const float* __restrict__ traw,
                                                 const float* __restrict__ rot,
                                                 const float* __restrict__ trans,
                                                 const int* __restrict__ patch_s,
                                                 const int* __restrict__ patch_t,
                                                 const int* __restrict__ corr,
                                                 const int* __restrict__ cnt_s,
                                                 const int* __restrict__ cnt_t,
                                                 float* __restrict__ out)
{
#pragma clang fp contract(off)
  int c = blockIdx.x, tid = threadIdx.x;
  int sn = corr[c*2], tn = corr[c*2+1];
  int cs = cnt_s[sn], ct = cnt_t[tn];
  __shared__ float sx[64], sy[64], sz[64], spp[64];
  __shared__ float txa[64], tya[64], tza[64], tpp[64];
  __shared__ float g[64][65];
  __shared__ float rowsum[64], colsum[64];
  if (tid < 64){
    int idx = patch_s[sn*KP + tid];
    float p0 = sraw[(long)idx*3], p1 = sraw[(long)idx*3+1], p2 = sraw[(long)idx*3+2];
    float a0 = fmaf(rot[2], p2, fmaf(rot[1], p1, rot[0]*p0)) + trans[0];
    float a1 = fmaf(rot[5], p2, fmaf(rot[4], p1, rot[3]*p0)) + trans[1];
    float a2 = fmaf(rot[8], p2, fmaf(rot[7], p1, rot[6]*p0)) + trans[2];
    sx[tid]=a0; sy[tid]=a1; sz[tid]=a2;
    spp[tid] = a0*a0 + a1*a1 + a2*a2;
  } else if (tid < 128){
    int l = tid - 64;
    int idx = patch_t[tn*KP + l];
    float p0 = traw[(long)idx*3], p1 = traw[(long)idx*3+1], p2 = traw[(long)idx*3+2];
    txa[l]=p0; tya[l]=p1; tza[l]=p2;
    tpp[l] = p0*p0 + p1*p1 + p2*p2;
  }
  __syncthreads();
  for (int e = tid; e < 4096; e += 256){
    int n = e >> 6, m = e & 63;
    float dot = fmaf(sz[n], tza[m], fmaf(sy[n], tya[m], sx[n]*txa[m]));
    float d2 = (spp[n] + tpp[m]) - 2.0f*dot;
    d2 = fmaxf(d2, 0.f);
    g[n][m] = (sqrtf(d2) < 0.1f) ? 1.f : 0.f;
  }
  __syncthreads();
  if (tid < 64){
    float s = 0.f;
    for (int m = 0; m < 64; ++m) s += g[tid][m];
    rowsum[tid] = fmaxf(1.f - s, 0.f);
  } else if (tid < 128){
    int m = tid - 64;
    float s = 0.f;
    for (int n = 0; n < 64; ++n) s += g[n][m];
    colsum[m] = fmaxf(1.f - s, 0.f);
  }
  __syncthreads();
  float* o = out + (long)c*4225;
  for (int e = tid; e < 4225; e += 256){
    int r = e / 65, col = e % 65;
    float v;
    if (r < 64 && col < 64) v = g[r][col];
    else if (r < 64)        v = rowsum[r];
    else if (col < 64)      v = colsum[col];
    else                    v = 0.f;
    if (r < 64 && r >= cs)    v = 0.f;
    if (col < 64 && col >= ct) v = 0.f;
    o[e] = v;
  }
}

// ======================= host =======================
extern "C" void kernel_launch(void* const* d_in, const int* in_sizes, int n_in,
                              void* d_out, int out_size, void* d_ws, size_t ws_size,
                              hipStream_t stream)
{
  const float* src_pcd_c  = (const float*)d_in[0];
  const float* tgt_pcd_c  = (const float*)d_in[1];
  const float* src_node_c = (const float*)d_in[2];
  const float* tgt_node_c = (const float*)d_in[3];
  const float* src_feats  = (const float*)d_in[4];
  const float* tgt_feats  = (const float*)d_in[5];
  const float* src_final  = (const float*)d_in[6];
  const float* tgt_final  = (const float*)d_in[7];
  const float* rot        = (const float*)d_in[8];
  const float* trans      = (const float*)d_in[9];
  const float* src_raw    = (const float*)d_in[10];
  const float* tgt_raw    = (const float*)d_in[11];
  const int*   node_corr  = (const int*)d_in[12];
  const float* c_wq = (const float*)d_in[13]; const float* c_bq = (const float*)d_in[14];
  const float* c_wk = (const float*)d_in[15]; const float* c_bk = (const float*)d_in[16];
  const float* c_wv = (const float*)d_in[17]; const float* c_bv = (const float*)d_in[18];
  const float* c_wm = (const float*)d_in[19]; const float* c_bm = (const float*)d_in[20];
  const float* c_w1 = (const float*)d_in[21]; const float* c_b1 = (const float*)d_in[22];
  const float* c_w2 = (const float*)d_in[23]; const float* c_b2 = (const float*)d_in[24];
  const float* l_wq = (const float*)d_in[25]; const float* l_bq = (const float*)d_in[26];
  const float* l_wk = (const float*)d_in[27]; const float* l_bk = (const float*)d_in[28];
  const float* l_wv = (const float*)d_in[29]; const float* l_bv = (const float*)d_in[30];
  const float* l_wm = (const float*)d_in[31]; const float* l_bm = (const float*)d_in[32];
  const float* l_w1 = (const float*)d_in[33]; const float* l_b1 = (const float*)d_in[34];
  const float* l_w2 = (const float*)d_in[35]; const float* l_b2 = (const float*)d_in[36];
  const float* fp_w = (const float*)d_in[37]; const float* fp_b = (const float*)d_in[38];
  const float* lfp_w = (const float*)d_in[39]; const float* lfp_b = (const float*)d_in[40];
  const float* bin_score = (const float*)d_in[41];

  const int NS = in_sizes[0] / 3;
  const int NT = in_sizes[1] / 3;

  float* FB = (float*)d_ws;
  size_t off = 0;
  auto falloc = [&](size_t n){ float* p = FB + off; off += (n + 63) & ~size_t(63); return p; };
  float* Zx  = falloc(263169);
  float* Zt  = falloc(263169);
  float* Rr  = falloc(640);
  float* Cc  = falloc(640);
  float* wu  = falloc(640);
  float* wvg = falloc(640);
  float* cff = falloc(262144);
  u16* cf   = (u16*)falloc(131072);
  u16* qb   = (u16*)falloc(131072);
  u16* kb   = (u16*)falloc(131072);
  u16* vtb  = (u16*)falloc(131072);
  u16* msgb = (u16*)falloc(131072);
  u16* sfpb = (u16*)falloc(131072);
  u16* X0   = (u16*)falloc(2097152);   // [2][256][64][128] bf16
  u16* wsb  = (u16*)falloc(1269760);

  int* IB = (int*)(FB + off);
  size_t ioff = 0;
  auto ialloc = [&](size_t n){ int* p = IB + ioff; ioff += (n + 63) & ~size_t(63); return p; };
  int* cntbar = ialloc(128);
  int* id_s = ialloc(NS);
  int* id_t = ialloc(NT);
  const int nbs = (NS + 255) / 256, nbt = (NT + 255) / 256;
  int* hist_s = ialloc((size_t)nbs * NODES);
  int* hist_t = ialloc((size_t)nbt * NODES);
  int* cnt_s = ialloc(NODES);
  int* cnt_t = ialloc(NODES);
  int* patch_s = ialloc(NODES*KP);
  int* patch_t = ialloc(NODES*KP);

  float* out0 = (float*)d_out;
  float* out_ls = out0 + ZDIM*ZDIM;
  float* out_gt = out_ls + (long)CC*65*65;

  u16* WcQ = wsb + 0;
  u16* WcK = wsb + 196608;
  u16* WcV = wsb + 393216;
  u16* WcM = wsb + 589824;
  u16* Wc1 = wsb + 786432;
  u16* Wc2 = wsb + 1572864;
  u16* Wfp = wsb + 1966080;
  u16* WlQ = wsb + 2031616;
  u16* WlK = wsb + 2080768;
  u16* WlV = wsb + 2129920;
  u16* WlM = wsb + 2179072;
  u16* Wl1 = wsb + 2228224;
  u16* Wl2 = wsb + 2424832;
  u16* Wlfp = wsb + 2523136;

  conv_weights<<<(2539520+255)/256, 256, 0, stream>>>(
      c_wq, c_wk, c_wv, c_wm, c_w1, c_w2, fp_w,
      l_wq, l_wk, l_wv, l_wm, l_w1, l_w2, lfp_w, wsb);

  // ---- NN + patches ----
  nn_kernel<<<nbs, 256, 0, stream>>>(src_pcd_c, NS, src_node_c, id_s);
  nn_kernel<<<nbt, 256, 0, stream>>>(tgt_pcd_c, NT, tgt_node_c, id_t);
  hist_kernel<<<nbs, 256, 0, stream>>>(id_s, NS, hist_s);
  hist_kernel<<<nbt, 256, 0, stream>>>(id_t, NT, hist_t);
  scan_kernel<<<1, 512, 0, stream>>>(hist_s, nbs, cnt_s);
  scan_kernel<<<1, 512, 0, stream>>>(hist_t, nbt, cnt_t);
  hipMemsetAsync(patch_s, 0, NODES*KP*sizeof(int), stream);
  hipMemsetAsync(patch_t, 0, NODES*KP*sizeof(int), stream);
  rank_kernel<<<nbs, 256, 0, stream>>>(id_s, NS, hist_s, patch_s);
  rank_kernel<<<nbt, 256, 0, stream>>>(id_t, NT, hist_t, patch_t);

  // ---- coarse transformer (sequential-cross semantics, matches reference) ----
  tr_in<<<1024, 256, 0, stream>>>(src_feats, tgt_feats, cf, cff);
  int crossL[3] = {0, 1, 0};
  for (int l = 0; l < 3; ++l){
    u16* wq = WcQ + (size_t)l*65536; u16* wk = WcK + (size_t)l*65536;
    u16* wv = WcV + (size_t)l*65536; u16* wm = WcM + (size_t)l*65536;
    u16* w1 = Wc1 + (size_t)l*262144; u16* w2 = Wc2 + (size_t)l*131072;
    const float* bq = c_bq + (size_t)l*256; const float* bk = c_bk + (size_t)l*256;
    const float* bv = c_bv + (size_t)l*256; const float* bm = c_bm + (size_t)l*256;
    const float* b1 = c_b1 + (size_t)l*512; const float* b2 = c_b2 + (size_t)l*256;
    if (!crossL[l]){
      coarse_qkv<<<48, 256, 0, stream>>>(cf, 0, 0, wq, wk, wv, bq, bk, bv, qb, kb, vtb);
      coarse_attn<<<64, 256, 0, stream>>>(qb, kb, vtb, msgb, 0);
      coarse_ffn<<<16, 512, 0, stream>>>(msgb, cf, cff, wm, bm, w1, b1, w2, b2, 0);
    } else {
      for (int sd = 0; sd < 2; ++sd){
        coarse_qkv<<<24, 256, 0, stream>>>(cf, 1, sd, wq, wk, wv, bq, bk, bv, qb, kb, vtb);
        coarse_attn<<<32, 256, 0, stream>>>(qb, kb, vtb, msgb, sd);
        coarse_ffn<<<8, 512, 0, stream>>>(msgb, cf, cff, wm, bm, w1, b1, w2, b2, sd);
      }
    }
  }
  coarse_proj<<<16, 256, 0, stream>>>(cf, Wfp, fp_b, sfpb);
  coarse_scores<<<dim3(8,8), 256, 0, stream>>>(sfpb, sfpb + 131072, Zx);
  fill_border<<<3, 256, 0, stream>>>(Zx, bin_score);

  // ---- transport (persistent, counter-slot barrier) ----
  transpose_k<<<dim3(17,17), 256, 0, stream>>>(Zx, Zt, ZDIM);
  hipMemsetAsync(cntbar, 0, 128*sizeof(int), stream);
  transport_persist<<<TPNB, 1024, 0, stream>>>(Zx, Zt, Rr, Cc, wu, wvg, out0, cntbar,
                                               logf(1024.0f));

  // ---- local transformer (in-place, sequential-cross) ----
  gather_feats<<<CC, 256, 0, stream>>>(src_final, patch_s, node_corr, 0, X0);
  gather_feats<<<CC, 256, 0, stream>>>(tgt_final, patch_t, node_corr, 1, X0 + 2097152);
  for (int l = 0; l < 3; ++l){
    u16* wq = WlQ + (size_t)l*16384; u16* wk = WlK + (size_t)l*16384;
    u16* wv = WlV + (size_t)l*16384; u16* wm = WlM + (size_t)l*16384;
    u16* w1 = Wl1 + (size_t)l*65536; u16* w2 = Wl2 + (size_t)l*32768;
    const float* bq = l_bq + (size_t)l*128; const float* bk = l_bk + (size_t)l*128;
    const float* bv = l_bv + (size_t)l*128; const float* bm = l_bm + (size_t)l*128;
    const float* b1 = l_b1 + (size_t)l*256; const float* b2 = l_b2 + (size_t)l*128;
    if (!crossL[l]){
      local_layer<<<512, 256, 0, stream>>>(X0, 0, 0, wq,wk,wv,wm,w1,w2, bq,bk,bv,bm,b1,b2);
    } else {
      local_layer<<<256, 256, 0, stream>>>(X0, 1, 0, wq,wk,wv,wm,w1,w2, bq,bk,bv,bm,b1,b2);
      local_layer<<<256, 256, 0, stream>>>(X0, 1, 1, wq,wk,wv,wm,w1,w2, bq,bk,bv,bm,b1,b2);
    }
  }
  sk_fused<<<CC, 1024, 0, stream>>>(X0, Wlfp, lfp_b, node_corr, cnt_s, cnt_t, out_ls);

  // ---- GT ----
  gt_kernel<<<CC, 256, 0, stream>>>(src_raw, tgt_raw, rot, trans,
                                    patch_s, patch_t, node_corr, cnt_s, cnt_t, out_gt);

  (void)n_in; (void)out_size; (void)ws_size;
}

// Round 6
// 1232.422 us; speedup vs baseline: 1.4890x; 1.1272x over previous
//
#include <hip/hip_runtime.h>
#include <math.h>

static constexpr int NODES = 512;
static constexpr int CC    = 256;
static constexpr int KP    = 64;
static constexpr int ZDIM  = 513;

typedef unsigned short u16;
typedef short bf16x8 __attribute__((ext_vector_type(8)));
typedef float f32x4 __attribute__((ext_vector_type(4)));

__device__ __forceinline__ u16 f2b(float f){
  unsigned u = __float_as_uint(f);
  unsigned r = (u + 0x7FFF + ((u >> 16) & 1)) >> 16;
  return (u16)r;
}
__device__ __forceinline__ float b2f(u16 h){ return __uint_as_float(((unsigned)h) << 16); }
__device__ __forceinline__ f32x4 mfma16(bf16x8 a, bf16x8 b, f32x4 c){
  return __builtin_amdgcn_mfma_f32_16x16x32_bf16(a, b, c, 0, 0, 0);
}

// ======================= NN + hist (fused, decision-exact) =======================
// grid nbs+nbt: block < nbs -> src cloud, else tgt.
__global__ __launch_bounds__(256) void nn_hist_kernel(
    const float* __restrict__ pts_s, int ns, const float* __restrict__ nodes_s,
    int* __restrict__ out_s, int* __restrict__ hist_s,
    const float* __restrict__ pts_t, int ntt, const float* __restrict__ nodes_t,
    int* __restrict__ out_t, int* __restrict__ hist_t, int nbs)
{
#pragma clang fp contract(off)
  __shared__ float nx[NODES], ny[NODES], nz[NODES], nn[NODES];
  __shared__ int h[NODES];
  int blk = blockIdx.x;
  const float* pts; const float* nodes; int* out; int* hist; int n; int bb;
  if (blk < nbs){ pts=pts_s; nodes=nodes_s; out=out_s; hist=hist_s; n=ns; bb=blk; }
  else          { pts=pts_t; nodes=nodes_t; out=out_t; hist=hist_t; n=ntt; bb=blk-nbs; }
  int t = threadIdx.x;
  for (int m = t; m < NODES; m += 256){
    float a = nodes[m*3+0], b = nodes[m*3+1], c = nodes[m*3+2];
    nx[m]=a; ny[m]=b; nz[m]=c;
    nn[m] = a*a + b*b + c*c;
    h[m] = 0;
  }
  __syncthreads();
  int i = bb*256 + t;
  if (i < n){
    float p0 = pts[i*3+0], p1 = pts[i*3+1], p2 = pts[i*3+2];
    float pp = p0*p0 + p1*p1 + p2*p2;
    float best = INFINITY; int bi = 0;
    for (int m = 0; m < NODES; ++m){
      float dot = fmaf(p2, nz[m], fmaf(p1, ny[m], p0*nx[m]));
      float d = (pp - 2.0f*dot) + nn[m];
      if (d < best){ best = d; bi = m; }
    }
    out[i] = bi;
    atomicAdd(&h[bi], 1);
  }
  __syncthreads();
  hist[(long)bb*NODES + t]       = h[t];
  hist[(long)bb*NODES + t + 256] = h[t+256];
}

// grid 2 blocks x 512 threads: block 0 = src, 1 = tgt
__global__ __launch_bounds__(512) void scan_kernel(
    int* __restrict__ hist_s, int nbs, int* __restrict__ cnt_s,
    int* __restrict__ hist_t, int nbt, int* __restrict__ cnt_t)
{
  int* hist; int nb; int* counts;
  if (blockIdx.x == 0){ hist=hist_s; nb=nbs; counts=cnt_s; }
  else                { hist=hist_t; nb=nbt; counts=cnt_t; }
  int m = threadIdx.x;
  int run = 0;
  for (int b = 0; b < nb; ++b){
    int t = hist[(long)b*NODES + m];
    hist[(long)b*NODES + m] = run;
    run += t;
  }
  counts[m] = run;
}

// grid nbs+nbt
__global__ __launch_bounds__(256) void rank_kernel(
    const int* __restrict__ id_s, int ns, const int* __restrict__ hist_s, int* __restrict__ patch_s,
    const int* __restrict__ id_t, int ntt, const int* __restrict__ hist_t, int* __restrict__ patch_t,
    int nbs)
{
  __shared__ int lid[256];
  int blk = blockIdx.x;
  const int* id; const int* hist; int* patch; int n; int bb;
  if (blk < nbs){ id=id_s; hist=hist_s; patch=patch_s; n=ns; bb=blk; }
  else          { id=id_t; hist=hist_t; patch=patch_t; n=ntt; bb=blk-nbs; }
  int t = threadIdx.x;
  int i = bb*256 + t;
  lid[t] = (i < n) ? id[i] : -1;
  __syncthreads();
  if (i >= n) return;
  int m = lid[t];
  int r = hist[(long)bb*NODES + m];
  for (int q = 0; q < t; ++q) r += (lid[q] == m) ? 1 : 0;
  if (r < KP) patch[m*KP + r] = i;
}

// ======================= weight conversion =======================
__global__ __launch_bounds__(256) void conv_weights(
  const float* cwq, const float* cwk, const float* cwv, const float* cwm,
  const float* cw1, const float* cw2, const float* fpw,
  const float* lwq, const float* lwk, const float* lwv, const float* lwm,
  const float* lw1, const float* lw2, const float* lfp,
  u16* __restrict__ dst)
{
  int i = blockIdx.x*256 + threadIdx.x;
  if (i >= 2539520) return;
  const float* s; int off;
  if      (i <  196608){ s=cwq; off=0; }
  else if (i <  393216){ s=cwk; off=196608; }
  else if (i <  589824){ s=cwv; off=393216; }
  else if (i <  786432){ s=cwm; off=589824; }
  else if (i < 1572864){ s=cw1; off=786432; }
  else if (i < 1966080){ s=cw2; off=1572864; }
  else if (i < 2031616){ s=fpw; off=1966080; }
  else if (i < 2080768){ s=lwq; off=2031616; }
  else if (i < 2129920){ s=lwk; off=2080768; }
  else if (i < 2179072){ s=lwv; off=2129920; }
  else if (i < 2228224){ s=lwm; off=2179072; }
  else if (i < 2424832){ s=lw1; off=2228224; }
  else if (i < 2523136){ s=lw2; off=2424832; }
  else                 { s=lfp; off=2523136; }
  dst[i] = f2b(s[i - off]);
}

__global__ __launch_bounds__(256) void tr_in(const float* __restrict__ fs,
                                             const float* __restrict__ ft,
                                             u16* __restrict__ cf,
                                             float* __restrict__ cff)
{
  int i = blockIdx.x*256 + threadIdx.x;
  if (i >= 262144) return;
  int side = i >> 17; int r = i & 131071; int d = r >> 9; int n = r & 511;
  float v = (side ? ft : fs)[r];
  long o = ((long)side*512 + n)*256 + d;
  cf[o] = f2b(v);
  cff[o] = v;
}

// ======================= coarse transformer (bf16 MFMA, [n][d]) =======================
__global__ __launch_bounds__(256) void coarse_qkv(
    const u16* __restrict__ cf, int cross, int side0,
    const u16* __restrict__ Wq, const u16* __restrict__ Wk, const u16* __restrict__ Wv,
    const float* __restrict__ bq, const float* __restrict__ bk, const float* __restrict__ bv,
    u16* __restrict__ qb, u16* __restrict__ kb, u16* __restrict__ vtb)
{
  int z = blockIdx.x;
  int side = side0 + z/24, rem = z%24, proj = rem >> 3, slice = rem & 7;
  const u16* x = cf + (long)side*131072;
  const u16* s = cross ? cf + (long)(1-side)*131072 : x;
  const u16* in = (proj == 0) ? x : s;
  const u16* W  = (proj==0)?Wq:(proj==1)?Wk:Wv;
  const float* bi = (proj==0)?bq:(proj==1)?bk:bv;
  int n0 = slice << 6;
  int wv_ = threadIdx.x >> 6, L = threadIdx.x & 63, lr = L & 15, lk = L >> 4;
  const u16* inb = in + (long)(n0 + lr)*256 + 8*lk;
  for (int oi = 0; oi < 4; ++oi){
    int o0 = (wv_*4 + oi) << 4;
    const u16* wrow = W + (long)(o0 + lr)*256 + 8*lk;
    f32x4 acc[4] = {};
#pragma unroll
    for (int ks = 0; ks < 8; ++ks){
      bf16x8 b = *(const bf16x8*)(wrow + ks*32);
#pragma unroll
      for (int a = 0; a < 4; ++a){
        bf16x8 av = *(const bf16x8*)(inb + a*16*256 + ks*32);
        acc[a] = mfma16(av, b, acc[a]);
      }
    }
    int col = o0 + lr;
    float bvv = bi[col];
    if (proj < 2){
      u16* o = (proj==0 ? qb : kb) + ((long)side*512 + n0)*256 + col;
#pragma unroll
      for (int a = 0; a < 4; ++a)
#pragma unroll
        for (int q_ = 0; q_ < 4; ++q_)
          o[(long)(a*16 + lk*4 + q_)*256] = f2b(acc[a][q_] + bvv);
    } else {
      u16* o = vtb + ((long)side*256 + col)*512 + n0;
#pragma unroll
      for (int a = 0; a < 4; ++a)
#pragma unroll
        for (int q_ = 0; q_ < 4; ++q_)
          o[a*16 + lk*4 + q_] = f2b(acc[a][q_] + bvv);
    }
  }
}

__global__ __launch_bounds__(256) void coarse_attn(
    const u16* __restrict__ qb, const u16* __restrict__ kb,
    const u16* __restrict__ vtb, u16* __restrict__ msgb, int side0)
{
  __shared__ u16 P[64][512];
  __shared__ float rmx[64][4], rsm[64][4];
  int z = blockIdx.x;
  int side = side0 + (z >> 5); int rem = z & 31;
  int head = rem >> 3, qs = rem & 7;
  int wv_ = threadIdx.x >> 6, L = threadIdx.x & 63, lr = L & 15, lk = L >> 4;
  const u16* q = qb + ((long)side*512 + qs*64)*256 + head*64;
  const u16* k = kb + (long)side*512*256 + head*64;
  const u16* vt = vtb + ((long)side*256 + head*64)*512;

  bf16x8 af[4][2];
#pragma unroll
  for (int a = 0; a < 4; ++a)
#pragma unroll
    for (int ks = 0; ks < 2; ++ks)
      af[a][ks] = *(const bf16x8*)(q + (long)(a*16 + lr)*256 + ks*32 + 8*lk);

  f32x4 sc[4][8] = {};
  for (int b = 0; b < 8; ++b){
    const u16* krow = k + (long)(wv_*128 + b*16 + lr)*256 + 8*lk;
#pragma unroll
    for (int ks = 0; ks < 2; ++ks){
      bf16x8 bf = *(const bf16x8*)(krow + ks*32);
#pragma unroll
      for (int a = 0; a < 4; ++a)
        sc[a][b] = mfma16(af[a][ks], bf, sc[a][b]);
    }
  }
  const float SC = 0.125f; // 1/sqrt(64)
#pragma unroll
  for (int a = 0; a < 4; ++a)
#pragma unroll
    for (int q_ = 0; q_ < 4; ++q_){
      float m = sc[a][0][q_];
#pragma unroll
      for (int b = 1; b < 8; ++b) m = fmaxf(m, sc[a][b][q_]);
      m = fmaxf(m, __shfl_xor(m, 1)); m = fmaxf(m, __shfl_xor(m, 2));
      m = fmaxf(m, __shfl_xor(m, 4)); m = fmaxf(m, __shfl_xor(m, 8));
      if (lr == 0) rmx[a*16 + lk*4 + q_][wv_] = m;
    }
  __syncthreads();
#pragma unroll
  for (int a = 0; a < 4; ++a)
#pragma unroll
    for (int q_ = 0; q_ < 4; ++q_){
      int row = a*16 + lk*4 + q_;
      float m = fmaxf(fmaxf(rmx[row][0], rmx[row][1]), fmaxf(rmx[row][2], rmx[row][3]));
      float s = 0.f;
#pragma unroll
      for (int b = 0; b < 8; ++b){
        float e = __expf((sc[a][b][q_] - m)*SC);
        sc[a][b][q_] = e; s += e;
      }
      s += __shfl_xor(s,1); s += __shfl_xor(s,2); s += __shfl_xor(s,4); s += __shfl_xor(s,8);
      if (lr == 0) rsm[row][wv_] = s;
    }
  __syncthreads();
#pragma unroll
  for (int a = 0; a < 4; ++a)
#pragma unroll
    for (int q_ = 0; q_ < 4; ++q_){
      int row = a*16 + lk*4 + q_;
      float inv = 1.f / (rsm[row][0]+rsm[row][1]+rsm[row][2]+rsm[row][3]);
#pragma unroll
      for (int b = 0; b < 8; ++b)
        P[row][wv_*128 + b*16 + lr] = f2b(sc[a][b][q_] * inv);
    }
  __syncthreads();
  f32x4 mv[4] = {};
  for (int ks = 0; ks < 16; ++ks){
    bf16x8 bf = *(const bf16x8*)(vt + (long)(wv_*16 + lr)*512 + ks*32 + 8*lk);
#pragma unroll
    for (int a = 0; a < 4; ++a){
      bf16x8 av = *(const bf16x8*)(&P[a*16 + lr][ks*32 + 8*lk]);
      mv[a] = mfma16(av, bf, mv[a]);
    }
  }
  u16* o = msgb + ((long)side*512 + qs*64)*256 + head*64 + wv_*16 + lr;
#pragma unroll
  for (int a = 0; a < 4; ++a)
#pragma unroll
    for (int q_ = 0; q_ < 4; ++q_)
      o[(long)(a*16 + lk*4 + q_)*256] = f2b(mv[a][q_]);
}

__global__ __launch_bounds__(512) void coarse_ffn(
    const u16* __restrict__ msgb, u16* __restrict__ cf, float* __restrict__ cff,
    const u16* __restrict__ Wm, const float* __restrict__ bm,
    const u16* __restrict__ W1, const float* __restrict__ b1,
    const u16* __restrict__ W2, const float* __restrict__ b2, int side0)
{
  __shared__ u16 m2[64*256];
  __shared__ u16 h1[64*512];
  int z = blockIdx.x;
  int side = side0 + (z >> 3), slice = z & 7;
  int wv_ = threadIdx.x >> 6, L = threadIdx.x & 63, lr = L & 15, lk = L >> 4;
  const u16* msg = msgb + ((long)side*512 + slice*64)*256;
  u16* x = cf + ((long)side*512 + slice*64)*256;
  float* xf = cff + ((long)side*512 + slice*64)*256;
  for (int oi = 0; oi < 2; ++oi){
    int o0 = (wv_*2 + oi) << 4;
    f32x4 acc[4] = {};
    const u16* wrow = Wm + (long)(o0+lr)*256 + 8*lk;
#pragma unroll
    for (int ks = 0; ks < 8; ++ks){
      bf16x8 b = *(const bf16x8*)(wrow + ks*32);
#pragma unroll
      for (int a = 0; a < 4; ++a){
        bf16x8 av = *(const bf16x8*)(msg + (long)(a*16+lr)*256 + ks*32 + 8*lk);
        acc[a] = mfma16(av, b, acc[a]);
      }
    }
    int col = o0 + lr; float bb = bm[col];
#pragma unroll
    for (int a = 0; a < 4; ++a)
#pragma unroll
      for (int q_ = 0; q_ < 4; ++q_)
        m2[(a*16+lk*4+q_)*256 + col] = f2b(acc[a][q_] + bb);
  }
  __syncthreads();
  for (int oi = 0; oi < 4; ++oi){
    int o0 = (wv_*4 + oi) << 4;
    f32x4 acc[4] = {};
    const u16* wrow = W1 + (long)(o0+lr)*512 + 8*lk;
#pragma unroll
    for (int ks = 0; ks < 16; ++ks){
      int kk = ks*32;
      bf16x8 b = *(const bf16x8*)(wrow + kk);
#pragma unroll
      for (int a = 0; a < 4; ++a){
        bf16x8 av;
        if (kk < 256) av = *(const bf16x8*)(x + (long)(a*16+lr)*256 + kk + 8*lk);
        else          av = *(const bf16x8*)(&m2[(a*16+lr)*256 + kk - 256 + 8*lk]);
        acc[a] = mfma16(av, b, acc[a]);
      }
    }
    int col = o0 + lr; float bb = b1[col];
#pragma unroll
    for (int a = 0; a < 4; ++a)
#pragma unroll
      for (int q_ = 0; q_ < 4; ++q_)
        h1[(a*16+lk*4+q_)*512 + col] = f2b(fmaxf(acc[a][q_] + bb, 0.f));
  }
  __syncthreads();
  for (int oi = 0; oi < 2; ++oi){
    int o0 = (wv_*2 + oi) << 4;
    f32x4 acc[4] = {};
    const u16* wrow = W2 + (long)(o0+lr)*512 + 8*lk;
#pragma unroll
    for (int ks = 0; ks < 16; ++ks){
      bf16x8 b = *(const bf16x8*)(wrow + ks*32);
#pragma unroll
      for (int a = 0; a < 4; ++a){
        bf16x8 av = *(const bf16x8*)(&h1[(a*16+lr)*512 + ks*32 + 8*lk]);
        acc[a] = mfma16(av, b, acc[a]);
      }
    }
    int col = o0 + lr; float bb = b2[col];
#pragma unroll
    for (int a = 0; a < 4; ++a)
#pragma unroll
      for (int q_ = 0; q_ < 4; ++q_){
        long idx = (long)(a*16+lk*4+q_)*256 + col;
        float v = acc[a][q_] + bb + xf[idx];
        xf[idx] = v;
        x[idx] = f2b(v);
      }
  }
}

__global__ __launch_bounds__(256) void coarse_proj(
    const u16* __restrict__ cf, const u16* __restrict__ W,
    const float* __restrict__ bias, u16* __restrict__ out)
{
  int z = blockIdx.x;
  int side = z >> 3, slice = z & 7;
  const u16* in = cf + (long)side*131072;
  u16* o = out + (long)side*131072;
  int n0 = slice << 6;
  int wv_ = threadIdx.x >> 6, L = threadIdx.x & 63, lr = L & 15, lk = L >> 4;
  const u16* inb = in + (long)(n0 + lr)*256 + 8*lk;
  for (int oi = 0; oi < 4; ++oi){
    int o0 = (wv_*4 + oi) << 4;
    const u16* wrow = W + (long)(o0 + lr)*256 + 8*lk;
    f32x4 acc[4] = {};
#pragma unroll
    for (int ks = 0; ks < 8; ++ks){
      bf16x8 b = *(const bf16x8*)(wrow + ks*32);
#pragma unroll
      for (int a = 0; a < 4; ++a){
        bf16x8 av = *(const bf16x8*)(inb + a*16*256 + ks*32);
        acc[a] = mfma16(av, b, acc[a]);
      }
    }
    int col = o0 + lr; float bb = bias[col];
#pragma unroll
    for (int a = 0; a < 4; ++a)
#pragma unroll
      for (int q_ = 0; q_ < 4; ++q_)
        o[(long)(n0 + a*16 + lk*4 + q_)*256 + col] = f2b(acc[a][q_] + bb);
  }
}

__global__ __launch_bounds__(256) void coarse_scores(
    const u16* __restrict__ sfp, const u16* __restrict__ tfp, float* __restrict__ Z)
{
  int n0 = blockIdx.y << 6, m0 = blockIdx.x << 6;
  int wv_ = threadIdx.x >> 6, L = threadIdx.x & 63, lr = L & 15, lk = L >> 4;
  f32x4 acc[4] = {};
  const u16* arow = sfp + (long)(n0 + lr)*256 + 8*lk;
  const u16* brow = tfp + (long)(m0 + wv_*16 + lr)*256 + 8*lk;
#pragma unroll
  for (int ks = 0; ks < 8; ++ks){
    bf16x8 b = *(const bf16x8*)(brow + ks*32);
#pragma unroll
    for (int a = 0; a < 4; ++a){
      bf16x8 av = *(const bf16x8*)(arow + a*16*256 + ks*32);
      acc[a] = mfma16(av, b, acc[a]);
    }
  }
  int col = m0 + wv_*16 + lr;
#pragma unroll
  for (int a = 0; a < 4; ++a)
#pragma unroll
    for (int q_ = 0; q_ < 4; ++q_)
      Z[(long)(n0 + a*16 + lk*4 + q_)*513 + col] = acc[a][q_]*0.0625f;
}

// ======================= transport =======================
__global__ __launch_bounds__(256) void fill_border(float* Z, const float* __restrict__ alpha)
{
  int i = blockIdx.x*256 + threadIdx.x;
  if (i < ZDIM){
    float a = alpha[0];
    Z[(long)i*ZDIM + (ZDIM-1)] = a;
    Z[(long)(ZDIM-1)*ZDIM + i] = a;
  }
}

__global__ __launch_bounds__(256) void transpose_k(const float* __restrict__ A,
                                                   float* __restrict__ B, int n)
{
  __shared__ float t[32][33];
  int bx = blockIdx.x*32, by = blockIdx.y*32;
  int lx = threadIdx.x & 31, ly0 = threadIdx.x >> 5;
  for (int dy = 0; dy < 32; dy += 8){
    int x = bx + lx, y = by + ly0 + dy;
    if (x < n && y < n) t[ly0+dy][lx] = A[(long)y*n + x];
  }
  __syncthreads();
  for (int dy = 0; dy < 32; dy += 8){
    int x = by + lx, y = bx + ly0 + dy;
    if (x < n && y < n) B[(long)y*n + x] = t[lx][ly0+dy];
  }
}

// persistent exp-domain sinkhorn, SENTINEL-DATAFLOW (no barriers):
// every cross-block dword is written once via relaxed agent atomic store into a
// per-iteration slot pre-set to 0xFFFFFFFF (NaN pattern, never a legit value);
// consumers poll that dword directly. Writers never wait.
static constexpr int TPNB = 16;
static constexpr int TPROWS = 33;

__device__ __forceinline__ void astore(float* p, float v){
  __hip_atomic_store(p, v, __ATOMIC_RELAXED, __HIP_MEMORY_SCOPE_AGENT);
}
__device__ __forceinline__ float fpoll(const float* p){
  const unsigned* up = (const unsigned*)p;
  unsigned v = __hip_atomic_load(up, __ATOMIC_RELAXED, __HIP_MEMORY_SCOPE_AGENT);
  while (v == 0xFFFFFFFFu)
    v = __hip_atomic_load(up, __ATOMIC_RELAXED, __HIP_MEMORY_SCOPE_AGENT);
  return __uint_as_float(v);
}

__global__ __launch_bounds__(1024) void transport_persist(
    const float* __restrict__ Z, const float* __restrict__ Zt,
    float* __restrict__ Rr, float* __restrict__ Cc,
    float* __restrict__ UU, float* __restrict__ VV,
    float* __restrict__ out, float outadd)
{
  __shared__ float A[TPROWS*513];
  __shared__ float B[TPROWS*513];
  __shared__ float RrL[513], CcL[513], M[513];
  __shared__ float rown[TPROWS], cown[TPROWS], uown[TPROWS];
  int bid = blockIdx.x, tid = threadIdx.x;
  int wv_ = tid >> 6, lane = tid & 63;
  int r0 = bid * TPROWS;
  int nr = 513 - r0; if (nr > TPROWS) nr = TPROWS;

  for (int i = wv_; i < nr; i += 16){
    const float* zr  = Z  + (long)(r0+i)*513;
    const float* ztr = Zt + (long)(r0+i)*513;
    for (int j = lane; j < 513; j += 64){ A[i*513+j] = zr[j]; B[i*513+j] = ztr[j]; }
  }
  __syncthreads();
  // rowmax of own Z rows -> Rr
  for (int i = wv_; i < nr; i += 16){
    float m = -INFINITY;
    for (int j = lane; j < 513; j += 64) m = fmaxf(m, A[i*513+j]);
    for (int o = 32; o; o >>= 1) m = fmaxf(m, __shfl_xor(m, o));
    if (lane == 0){ rown[i] = m; astore(&Rr[r0+i], m); }
  }
  if (tid < 513) RrL[tid] = fpoll(&Rr[tid]);
  __syncthreads();
  // colmax: Cc[r] = max_j (Zt[r][j] - Rr[j])
  for (int i = wv_; i < nr; i += 16){
    float m = -INFINITY;
    for (int j = lane; j < 513; j += 64) m = fmaxf(m, B[i*513+j] - RrL[j]);
    for (int o = 32; o; o >>= 1) m = fmaxf(m, __shfl_xor(m, o));
    if (lane == 0){ cown[i] = m; astore(&Cc[r0+i], m); }
  }
  if (tid < 513) CcL[tid] = fpoll(&Cc[tid]);
  __syncthreads();
  // exponentiate in place
  for (int i = wv_; i < nr; i += 16){
    float ro = rown[i], co = cown[i];
    for (int j = lane; j < 513; j += 64){
      A[i*513+j] = __expf(A[i*513+j] - ro - CcL[j]);
      B[i*513+j] = __expf(B[i*513+j] - co - RrL[j]);
    }
  }
  __syncthreads();
  const float EBM = 1.0f/1024.0f, EBL = 0.5f;
  // u-phase it=0 (implicit v = 1)
  for (int i = wv_; i < nr; i += 16){
    float s = 0.f;
    for (int j = lane; j < 513; j += 64) s += A[i*513+j];
    for (int o = 32; o; o >>= 1) s += __shfl_xor(s, o);
    if (lane == 0){
      int r = r0+i; float u = ((r < 512) ? EBM : EBL) / s;
      uown[i] = u; astore(&UU[r], u);
    }
  }
  for (int it = 0; it < 50; ++it){
    // v-phase it: consume UU[it]
    if (tid < 513) M[tid] = fpoll(&UU[(long)it*640 + tid]);
    __syncthreads();
    for (int i = wv_; i < nr; i += 16){
      float s = 0.f;
      for (int j = lane; j < 513; j += 64) s = fmaf(B[i*513+j], M[j], s);
      for (int o = 32; o; o >>= 1) s += __shfl_xor(s, o);
      if (lane == 0){
        int r = r0+i;
        astore(&VV[(long)it*640 + r], ((r < 512) ? EBM : EBL) / s);
      }
    }
    __syncthreads();
    if (it == 49) break;
    // u-phase it+1: consume VV[it]
    if (tid < 513) M[tid] = fpoll(&VV[(long)it*640 + tid]);
    __syncthreads();
    for (int i = wv_; i < nr; i += 16){
      float s = 0.f;
      for (int j = lane; j < 513; j += 64) s = fmaf(A[i*513+j], M[j], s);
      for (int o = 32; o; o >>= 1) s += __shfl_xor(s, o);
      if (lane == 0){
        int r = r0+i; float u = ((r < 512) ? EBM : EBL) / s;
        uown[i] = u; astore(&UU[(long)(it+1)*640 + r], u);
      }
    }
    __syncthreads();
  }
  // epilogue: final v = VV[49]
  if (tid < 513) M[tid] = fpoll(&VV[49L*640 + tid]);
  __syncthreads();
  for (int j = tid; j < 513; j += 1024) M[j] = __logf(M[j]) - CcL[j];
  __syncthreads();
  for (int i = wv_; i < nr; i += 16){
    int r = r0 + i;
    float uu = __logf(uown[i]) - rown[i];
    const float* zr = Z + (long)r*513;
    float* orow = out + (long)r*513;
    for (int j = lane; j < 513; j += 64) orow[j] = zr[j] + uu + M[j] + outadd;
  }
}

// ======================= local gather (fused both sides, bf16 [side][c][n][d]) =======================
__global__ __launch_bounds__(256) void gather_feats(
    const float* __restrict__ Fs, const float* __restrict__ Ft,
    const int* __restrict__ patch_s, const int* __restrict__ patch_t,
    const int* __restrict__ corr, u16* __restrict__ out)
{
  int z = blockIdx.x;
  int side = z >> 8, c = z & 255;
  const float* F = side ? Ft : Fs;
  const int* patch = side ? patch_t : patch_s;
  __shared__ int sel[KP];
  int tid = threadIdx.x;
  if (tid < KP){
    int node = corr[c*2 + side];
    sel[tid] = patch[node*KP + tid];
  }
  __syncthreads();
  u16* o = out + ((long)side*256 + c)*8192;
  for (int e = tid; e < KP*128; e += 256){
    int n = e >> 7, d = e & 127;
    o[(long)n*128 + d] = f2b(F[(long)sel[n]*128 + d]);
  }
}

// ======================= fused local transformer layer (in-place, sequential-cross) =======================
__global__ __launch_bounds__(256) void local_layer(
    u16* __restrict__ X, int cross, int side0,
    const u16* __restrict__ Wq, const u16* __restrict__ Wk,
    const u16* __restrict__ Wv, const u16* __restrict__ Wm,
    const u16* __restrict__ W1, const u16* __restrict__ W2,
    const float* __restrict__ bq, const float* __restrict__ bk,
    const float* __restrict__ bv, const float* __restrict__ bm,
    const float* __restrict__ b1, const float* __restrict__ b2)
{
  __shared__ u16 pool[32768];
  int z = blockIdx.x;
  int side = side0 + (z >> 8), c = z & 255;
  u16* x = X + ((long)side*256 + c)*8192;
  const u16* s = X + ((long)(cross ? 1-side : side)*256 + c)*8192;
  int wv_ = threadIdx.x >> 6, L = threadIdx.x & 63, lr = L & 15, lk = L >> 4;
  u16* qS = pool; u16* kS = pool + 8192; u16* vT = pool + 16384; u16* msgS = pool + 24576;

#pragma unroll
  for (int proj = 0; proj < 3; ++proj){
    const u16* in = proj ? s : x;
    const u16* W = proj==0?Wq:proj==1?Wk:Wv;
    const float* bi = proj==0?bq:proj==1?bk:bv;
#pragma unroll
    for (int oi = 0; oi < 2; ++oi){
      int o0 = (wv_ + oi*4) << 4;
      f32x4 acc[4] = {};
      const u16* wrow = W + (long)(o0+lr)*128 + 8*lk;
      const u16* inr = in + (long)lr*128 + 8*lk;
#pragma unroll
      for (int ks = 0; ks < 4; ++ks){
        bf16x8 b = *(const bf16x8*)(wrow + ks*32);
#pragma unroll
        for (int a = 0; a < 4; ++a){
          bf16x8 av = *(const bf16x8*)(inr + a*16*128 + ks*32);
          acc[a] = mfma16(av, b, acc[a]);
        }
      }
      int col = o0 + lr; float bb = bi[col];
      if (proj < 2){
        u16* dst = (proj==0 ? qS : kS);
#pragma unroll
        for (int a = 0; a < 4; ++a)
#pragma unroll
          for (int q_ = 0; q_ < 4; ++q_)
            dst[(a*16 + lk*4 + q_)*128 + col] = f2b(acc[a][q_] + bb);
      } else {
#pragma unroll
        for (int a = 0; a < 4; ++a)
#pragma unroll
          for (int q_ = 0; q_ < 4; ++q_)
            vT[col*64 + a*16 + lk*4 + q_] = f2b(acc[a][q_] + bb);
      }
    }
  }
  __syncthreads();
  int h = wv_;
  bf16x8 qf[4], kf[4];
#pragma unroll
  for (int a = 0; a < 4; ++a){
    qf[a] = *(const bf16x8*)(&qS[(a*16+lr)*128 + h*32 + 8*lk]);
    kf[a] = *(const bf16x8*)(&kS[(a*16+lr)*128 + h*32 + 8*lk]);
  }
  f32x4 sc[4][4] = {};
#pragma unroll
  for (int b = 0; b < 4; ++b)
#pragma unroll
    for (int a = 0; a < 4; ++a)
      sc[a][b] = mfma16(qf[a], kf[b], sc[a][b]);
  const float SCs = 0.17677669529663687f;
  float invs[4][4];
#pragma unroll
  for (int a = 0; a < 4; ++a)
#pragma unroll
    for (int q_ = 0; q_ < 4; ++q_){
      float m = sc[a][0][q_];
#pragma unroll
      for (int b = 1; b < 4; ++b) m = fmaxf(m, sc[a][b][q_]);
      m = fmaxf(m, __shfl_xor(m, 1)); m = fmaxf(m, __shfl_xor(m, 2));
      m = fmaxf(m, __shfl_xor(m, 4)); m = fmaxf(m, __shfl_xor(m, 8));
      float ss = 0.f;
#pragma unroll
      for (int b = 0; b < 4; ++b){
        float e = __expf((sc[a][b][q_] - m)*SCs);
        sc[a][b][q_] = e; ss += e;
      }
      ss += __shfl_xor(ss,1); ss += __shfl_xor(ss,2); ss += __shfl_xor(ss,4); ss += __shfl_xor(ss,8);
      invs[a][q_] = 1.f/ss;
    }
  __syncthreads();
  u16* P = pool + h*4096;
#pragma unroll
  for (int a = 0; a < 4; ++a)
#pragma unroll
    for (int q_ = 0; q_ < 4; ++q_)
#pragma unroll
      for (int b = 0; b < 4; ++b)
        P[(a*16 + lk*4 + q_)*64 + b*16 + lr] = f2b(sc[a][b][q_] * invs[a][q_]);
  f32x4 mv[4][2] = {};
#pragma unroll
  for (int ks = 0; ks < 2; ++ks)
#pragma unroll
    for (int bt = 0; bt < 2; ++bt){
      bf16x8 bf = *(const bf16x8*)(&vT[(h*32 + bt*16 + lr)*64 + ks*32 + 8*lk]);
#pragma unroll
      for (int a = 0; a < 4; ++a){
        bf16x8 av = *(const bf16x8*)(&P[(a*16+lr)*64 + ks*32 + 8*lk]);
        mv[a][bt] = mfma16(av, bf, mv[a][bt]);
      }
    }
#pragma unroll
  for (int a = 0; a < 4; ++a)
#pragma unroll
    for (int bt = 0; bt < 2; ++bt)
#pragma unroll
      for (int q_ = 0; q_ < 4; ++q_)
        msgS[(a*16 + lk*4 + q_)*128 + h*32 + bt*16 + lr] = f2b(mv[a][bt][q_]);
  __syncthreads();
  u16* m2 = pool;
#pragma unroll
  for (int oi = 0; oi < 2; ++oi){
    int o0 = (wv_ + oi*4) << 4;
    f32x4 acc[4] = {};
    const u16* wrow = Wm + (long)(o0+lr)*128 + 8*lk;
#pragma unroll
    for (int ks = 0; ks < 4; ++ks){
      bf16x8 b = *(const bf16x8*)(wrow + ks*32);
#pragma unroll
      for (int a = 0; a < 4; ++a){
        bf16x8 av = *(const bf16x8*)(&msgS[(a*16+lr)*128 + ks*32 + 8*lk]);
        acc[a] = mfma16(av, b, acc[a]);
      }
    }
    int col = o0+lr; float bb = bm[col];
#pragma unroll
    for (int a = 0; a < 4; ++a)
#pragma unroll
      for (int q_ = 0; q_ < 4; ++q_)
        m2[(a*16+lk*4+q_)*128 + col] = f2b(acc[a][q_] + bb);
  }
  __syncthreads();
  u16* h1 = pool + 8192;
#pragma unroll
  for (int oi = 0; oi < 4; ++oi){
    int o0 = (wv_*4 + oi) << 4;
    f32x4 acc[4] = {};
    const u16* wrow = W1 + (long)(o0+lr)*256 + 8*lk;
#pragma unroll
    for (int ks = 0; ks < 8; ++ks){
      int kk = ks*32;
      bf16x8 b = *(const bf16x8*)(wrow + kk);
#pragma unroll
      for (int a = 0; a < 4; ++a){
        bf16x8 av;
        if (kk < 128) av = *(const bf16x8*)(x + (long)(a*16+lr)*128 + kk + 8*lk);
        else          av = *(const bf16x8*)(&m2[(a*16+lr)*128 + kk - 128 + 8*lk]);
        acc[a] = mfma16(av, b, acc[a]);
      }
    }
    int col = o0+lr; float bb = b1[col];
#pragma unroll
    for (int a = 0; a < 4; ++a)
#pragma unroll
      for (int q_ = 0; q_ < 4; ++q_)
        h1[(a*16+lk*4+q_)*256 + col] = f2b(fmaxf(acc[a][q_] + bb, 0.f));
  }
  __syncthreads();
#pragma unroll
  for (int oi = 0; oi < 2; ++oi){
    int o0 = (wv_ + oi*4) << 4;
    f32x4 acc[4] = {};
    const u16* wrow = W2 + (long)(o0+lr)*256 + 8*lk;
#pragma unroll
    for (int ks = 0; ks < 8; ++ks){
      bf16x8 b = *(const bf16x8*)(wrow + ks*32);
#pragma unroll
      for (int a = 0; a < 4; ++a){
        bf16x8 av = *(const bf16x8*)(&h1[(a*16+lr)*256 + ks*32 + 8*lk]);
        acc[a] = mfma16(av, b, acc[a]);
      }
    }
    int col = o0+lr; float bb = b2[col];
#pragma unroll
    for (int a = 0; a < 4; ++a)
#pragma unroll
      for (int q_ = 0; q_ < 4; ++q_){
        int ri = (a*16+lk*4+q_)*128 + col;
        x[ri] = f2b(acc[a][q_] + bb + b2f(x[ri]));
      }
  }
}

// ======================= fused lfp + scores + multiplicative sinkhorn =======================
__global__ __launch_bounds__(1024) void sk_fused(
    const u16* __restrict__ X, const u16* __restrict__ lfpW, const float* __restrict__ lfpB,
    const int* __restrict__ corr, const int* __restrict__ cnt_s,
    const int* __restrict__ cnt_t, float* __restrict__ out)
{
  __shared__ u16 sptp[16384];
  __shared__ float LA[65][66];
  __shared__ float ET[65*66];
  __shared__ float uvec[65], vvec[65], u0s[65], Ul[65], Vl[65];
  float* E = (float*)sptp;
  u16* sp = sptp; u16* tp = sptp + 8192;
  int cpat = blockIdx.x;
  int tid = threadIdx.x;
  int wv_ = tid >> 6, L = tid & 63, lr = L & 15, lk = L >> 4;

  {
    const u16* in = X + ((long)((wv_>>3)*256 + cpat))*8192;
    u16* dst = (wv_ < 8) ? sp : tp;
    int o0 = (wv_ & 7) << 4;
    f32x4 acc[4] = {};
    const u16* wrow = lfpW + (long)(o0+lr)*128 + 8*lk;
    const u16* inr = in + (long)lr*128 + 8*lk;
#pragma unroll
    for (int ks = 0; ks < 4; ++ks){
      bf16x8 b = *(const bf16x8*)(wrow + ks*32);
#pragma unroll
      for (int a = 0; a < 4; ++a){
        bf16x8 av = *(const bf16x8*)(inr + a*16*128 + ks*32);
        acc[a] = mfma16(av, b, acc[a]);
      }
    }
    int col = o0 + lr; float bb = lfpB[col];
#pragma unroll
    for (int a = 0; a < 4; ++a)
#pragma unroll
      for (int q_ = 0; q_ < 4; ++q_)
        dst[(a*16 + lk*4 + q_)*128 + col] = f2b(acc[a][q_] + bb);
  }
  __syncthreads();
  int cs = cnt_s[corr[cpat*2]], ct = cnt_t[corr[cpat*2+1]];
  {
    int mt = wv_ >> 2, nt = wv_ & 3;
    f32x4 acc = {};
    const u16* arow = sp + (mt*16 + lr)*128 + 8*lk;
    const u16* brow = tp + (nt*16 + lr)*128 + 8*lk;
#pragma unroll
    for (int ks = 0; ks < 4; ++ks){
      bf16x8 a = *(const bf16x8*)(arow + ks*32);
      bf16x8 b = *(const bf16x8*)(brow + ks*32);
      acc = mfma16(a, b, acc);
    }
    const float SCS = 0.08838834764831845f;
#pragma unroll
    for (int q_ = 0; q_ < 4; ++q_){
      int row = mt*16 + lk*4 + q_;
      int col = nt*16 + lr;
      float v = acc[q_] * SCS;
      if (row >= cs || col >= ct) v = -1000000.0f;
      LA[row][col] = v;
    }
  }
  if (tid < 65){ LA[64][tid] = 0.f; LA[tid][64] = 0.f; uvec[tid] = 1.f; vvec[tid] = 1.f; }
  __syncthreads();
  int g = tid >> 4, sub = tid & 15;
  {
    float mx = -INFINITY;
    for (int j = sub; j < 65; j += 16) mx = fmaxf(mx, LA[g][j]);
    mx = fmaxf(mx, __shfl_xor(mx, 1)); mx = fmaxf(mx, __shfl_xor(mx, 2));
    mx = fmaxf(mx, __shfl_xor(mx, 4)); mx = fmaxf(mx, __shfl_xor(mx, 8));
    float s = 0.f;
    for (int j = sub; j < 65; j += 16) s += __expf(LA[g][j] - mx);
    s += __shfl_xor(s,1); s += __shfl_xor(s,2); s += __shfl_xor(s,4); s += __shfl_xor(s,8);
    float u0 = mx + __logf(s);
    if (sub == 0) u0s[g] = u0;
    for (int j = sub; j < 65; j += 16){
      float e = __expf(LA[g][j] - u0);
      E[g*66 + j] = e;
      ET[j*66 + g] = e;
    }
  }
  if (tid < 65){
    E[64*66 + tid] = 1.f;
    ET[tid*66 + 64] = 1.f;
    if (tid == 64) u0s[64] = 0.f;
  }
  __syncthreads();
  for (int it = 0; it < 50; ++it){
    {
      float s = 0.f;
      for (int r = sub; r < 65; r += 16) s = fmaf(ET[g*66 + r], uvec[r], s);
      s += __shfl_xor(s,1); s += __shfl_xor(s,2); s += __shfl_xor(s,4); s += __shfl_xor(s,8);
      if (sub == 0) vvec[g] = 1.f / s;
    }
    __syncthreads();
    if (it == 49) break;
    {
      float s = 0.f;
      for (int j = sub; j < 65; j += 16) s = fmaf(E[g*66 + j], vvec[j], s);
      s += __shfl_xor(s,1); s += __shfl_xor(s,2); s += __shfl_xor(s,4); s += __shfl_xor(s,8);
      if (sub == 0) uvec[g] = 1.f / s;
    }
    __syncthreads();
  }
  __syncthreads();
  if (tid < 65){ Ul[tid] = u0s[tid] - __logf(uvec[tid]); Vl[tid] = -__logf(vvec[tid]); }
  __syncthreads();
  for (int e = tid; e < 4225; e += 1024){
    int r = e / 65, c2 = e % 65;
    out[(long)cpat*4225 + e] = LA[r][c2] - Ul[r] - Vl[c2];
  }
}

// ======================= GT (decision-exact) =======================
__global__ __launch_bounds__(256) void gt_kernel(const float* __restrict__ sraw,
                                                 const float* __restrict__ traw,
                                                 const float* __restrict__ rot,
                                                 const float* __restrict__ trans,
                                                 const int* __restrict__ patch_s,
                                                 const int* __restrict__ patch_t,
                                                 const int* __restrict__ corr,
                                                 const int* __restrict__ cnt_s,
                                                 const int* __restrict__ cnt_t,
                                                 float* __restrict__ out)
{
#pragma clang fp contract(off)
  int c = blockIdx.x, tid = threadIdx.x;
  int sn = corr[c*2], tn = corr[c*2+1];
  int cs = cnt_s[sn], ct = cnt_t[tn];
  __shared__ float sx[64], sy[64], sz[64], spp[64];
  __shared__ float txa[64], tya[64], tza[64], tpp[64];
  __shared__ float g[64][65];
  __shared__ float rowsum[64], colsum[64];
  if (tid < 64){
    int idx = patch_s[sn*KP + tid];
    float p0 = sraw[(long)idx*3], p1 = sraw[(long)idx*3+1], p2 = sraw[(long)idx*3+2];
    float a0 = fmaf(rot[2], p2, fmaf(rot[1], p1, rot[0]*p0)) + trans[0];
    float a1 = fmaf(rot[5], p2, fmaf(rot[4], p1, rot[3]*p0)) + trans[1];
    float a2 = fmaf(rot[8], p2, fmaf(rot[7], p1, rot[6]*p0)) + trans[2];
    sx[tid]=a0; sy[tid]=a1; sz[tid]=a2;
    spp[tid] = a0*a0 + a1*a1 + a2*a2;
  } else if (tid < 128){
    int l = tid - 64;
    int idx = patch_t[tn*KP + l];
    float p0 = traw[(long)idx*3], p1 = traw[(long)idx*3+1], p2 = traw[(long)idx*3+2];
    txa[l]=p0; tya[l]=p1; tza[l]=p2;
    tpp[l] = p0*p0 + p1*p1 + p2*p2;
  }
  __syncthreads();
  for (int e = tid; e < 4096; e += 256){
    int n = e >> 6, m = e & 63;
    float dot = fmaf(sz[n], tza[m], fmaf(sy[n], tya[m], sx[n]*txa[m]));
    float d2 = (spp[n] + tpp[m]) - 2.0f*dot;
    d2 = fmaxf(d2, 0.f);
    g[n][m] = (sqrtf(d2) < 0.1f) ? 1.f : 0.f;
  }
  __syncthreads();
  if (tid < 64){
    float s = 0.f;
    for (int m = 0; m < 64; ++m) s += g[tid][m];
    rowsum[tid] = fmaxf(1.f - s, 0.f);
  } else if (tid < 128){
    int m = tid - 64;
    float s = 0.f;
    for (int n = 0; n < 64; ++n) s += g[n][m];
    colsum[m] = fmaxf(1.f - s, 0.f);
  }
  __syncthreads();
  float* o = out + (long)c*4225;
  for (int e = tid; e < 4225; e += 256){
    int r = e / 65, col = e % 65;
    float v;
    if (r < 64 && col < 64) v = g[r][col];
    else if (r < 64)        v = rowsum[r];
    else if (col < 64)      v = colsum[col];
    else                    v = 0.f;
    if (r < 64 && r >= cs)    v = 0.f;
    if (col < 64 && col >= ct) v = 0.f;
    o[e] = v;
  }
}

// ======================= host =======================
extern "C" void kernel_launch(void* const* d_in, const int* in_sizes, int n_in,
                              void* d_out, int out_size, void* d_ws, size_t ws_size,
                              hipStream_t stream)
{
  const float* src_pcd_c  = (const float*)d_in[0];
  const float* tgt_pcd_c  = (const float*)d_in[1];
  const float* src_node_c = (const float*)d_in[2];
  const float* tgt_node_c = (const float*)d_in[3];
  const float* src_feats  = (const float*)d_in[4];
  const float* tgt_feats  = (const float*)d_in[5];
  const float* src_final  = (const float*)d_in[6];
  const float* tgt_final  = (const float*)d_in[7];
  const float* rot        = (const float*)d_in[8];
  const float* trans      = (const float*)d_in[9];
  const float* src_raw    = (const float*)d_in[10];
  const float* tgt_raw    = (const float*)d_in[11];
  const int*   node_corr  = (const int*)d_in[12];
  const float* c_wq = (const float*)d_in[13]; const float* c_bq = (const float*)d_in[14];
  const float* c_wk = (const float*)d_in[15]; const float* c_bk = (const float*)d_in[16];
  const float* c_wv = (const float*)d_in[17]; const float* c_bv = (const float*)d_in[18];
  const float* c_wm = (const float*)d_in[19]; const float* c_bm = (const float*)d_in[20];
  const float* c_w1 = (const float*)d_in[21]; const float* c_b1 = (const float*)d_in[22];
  const float* c_w2 = (const float*)d_in[23]; const float* c_b2 = (const float*)d_in[24];
  const float* l_wq = (const float*)d_in[25]; const float* l_bq = (const float*)d_in[26];
  const float* l_wk = (const float*)d_in[27]; const float* l_bk = (const float*)d_in[28];
  const float* l_wv = (const float*)d_in[29]; const float* l_bv = (const float*)d_in[30];
  const float* l_wm = (const float*)d_in[31]; const float* l_bm = (const float*)d_in[32];
  const float* l_w1 = (const float*)d_in[33]; const float* l_b1 = (const float*)d_in[34];
  const float* l_w2 = (const float*)d_in[35]; const float* l_b2 = (const float*)d_in[36];
  const float* fp_w = (const float*)d_in[37]; const float* fp_b = (const float*)d_in[38];
  const float* lfp_w = (const float*)d_in[39]; const float* lfp_b = (const float*)d_in[40];
  const float* bin_score = (const float*)d_in[41];

  const int NS = in_sizes[0] / 3;
  const int NT = in_sizes[1] / 3;

  float* FB = (float*)d_ws;
  size_t off = 0;
  auto falloc = [&](size_t n){ float* p = FB + off; off += (n + 63) & ~size_t(63); return p; };
  float* Zx  = falloc(263169);
  float* Zt  = falloc(263169);
  // sentinel region (contiguous; one memset covers all four)
  float* Rr  = falloc(640);
  float* Cc  = falloc(640);
  float* UU  = falloc(32000);   // [50][640]
  float* VV  = falloc(32000);   // [50][640]
  float* cff = falloc(262144);
  u16* cf   = (u16*)falloc(131072);
  u16* qb   = (u16*)falloc(131072);
  u16* kb   = (u16*)falloc(131072);
  u16* vtb  = (u16*)falloc(131072);
  u16* msgb = (u16*)falloc(131072);
  u16* sfpb = (u16*)falloc(131072);
  u16* X0   = (u16*)falloc(2097152);   // [2][256][64][128] bf16
  u16* wsb  = (u16*)falloc(1269760);

  int* IB = (int*)(FB + off);
  size_t ioff = 0;
  auto ialloc = [&](size_t n){ int* p = IB + ioff; ioff += (n + 63) & ~size_t(63); return p; };
  int* id_s = ialloc(NS);
  int* id_t = ialloc(NT);
  const int nbs = (NS + 255) / 256, nbt = (NT + 255) / 256;
  int* hist_s = ialloc((size_t)nbs * NODES);
  int* hist_t = ialloc((size_t)nbt * NODES);
  int* cnt_s = ialloc(NODES);
  int* cnt_t = ialloc(NODES);
  int* patch_s = ialloc(NODES*KP);
  int* patch_t = ialloc(NODES*KP);

  float* out0 = (float*)d_out;
  float* out_ls = out0 + ZDIM*ZDIM;
  float* out_gt = out_ls + (long)CC*65*65;

  u16* WcQ = wsb + 0;
  u16* WcK = wsb + 196608;
  u16* WcV = wsb + 393216;
  u16* WcM = wsb + 589824;
  u16* Wc1 = wsb + 786432;
  u16* Wc2 = wsb + 1572864;
  u16* Wfp = wsb + 1966080;
  u16* WlQ = wsb + 2031616;
  u16* WlK = wsb + 2080768;
  u16* WlV = wsb + 2129920;
  u16* WlM = wsb + 2179072;
  u16* Wl1 = wsb + 2228224;
  u16* Wl2 = wsb + 2424832;
  u16* Wlfp = wsb + 2523136;

  // sentinel fill for the dataflow transport (re-runs on every graph replay)
  hipMemsetAsync(Rr, 0xFF, (640 + 640 + 32000 + 32000)*sizeof(float), stream);

  conv_weights<<<(2539520+255)/256, 256, 0, stream>>>(
      c_wq, c_wk, c_wv, c_wm, c_w1, c_w2, fp_w,
      l_wq, l_wk, l_wv, l_wm, l_w1, l_w2, lfp_w, wsb);

  // ---- NN + patches (fused pairs) ----
  nn_hist_kernel<<<nbs + nbt, 256, 0, stream>>>(
      src_pcd_c, NS, src_node_c, id_s, hist_s,
      tgt_pcd_c, NT, tgt_node_c, id_t, hist_t, nbs);
  scan_kernel<<<2, 512, 0, stream>>>(hist_s, nbs, cnt_s, hist_t, nbt, cnt_t);
  hipMemsetAsync(patch_s, 0, NODES*KP*sizeof(int), stream);
  hipMemsetAsync(patch_t, 0, NODES*KP*sizeof(int), stream);
  rank_kernel<<<nbs + nbt, 256, 0, stream>>>(
      id_s, NS, hist_s, patch_s, id_t, NT, hist_t, patch_t, nbs);

  // ---- coarse transformer (sequential-cross semantics) ----
  tr_in<<<1024, 256, 0, stream>>>(src_feats, tgt_feats, cf, cff);
  int crossL[3] = {0, 1, 0};
  for (int l = 0; l < 3; ++l){
    u16* wq = WcQ + (size_t)l*65536; u16* wk = WcK + (size_t)l*65536;
    u16* wv = WcV + (size_t)l*65536; u16* wm = WcM + (size_t)l*65536;
    u16* w1 = Wc1 + (size_t)l*262144; u16* w2 = Wc2 + (size_t)l*131072;
    const float* bq = c_bq + (size_t)l*256; const float* bk = c_bk + (size_t)l*256;
    const float* bv = c_bv + (size_t)l*256; const float* bm = c_bm + (size_t)l*256;
    const float* b1 = c_b1 + (size_t)l*512; const float* b2 = c_b2 + (size_t)l*256;
    if (!crossL[l]){
      coarse_qkv<<<48, 256, 0, stream>>>(cf, 0, 0, wq, wk, wv, bq, bk, bv, qb, kb, vtb);
      coarse_attn<<<64, 256, 0, stream>>>(qb, kb, vtb, msgb, 0);
      coarse_ffn<<<16, 512, 0, stream>>>(msgb, cf, cff, wm, bm, w1, b1, w2, b2, 0);
    } else {
      for (int sd = 0; sd < 2; ++sd){
        coarse_qkv<<<24, 256, 0, stream>>>(cf, 1, sd, wq, wk, wv, bq, bk, bv, qb, kb, vtb);
        coarse_attn<<<32, 256, 0, stream>>>(qb, kb, vtb, msgb, sd);
        coarse_ffn<<<8, 512, 0, stream>>>(msgb, cf, cff, wm, bm, w1, b1, w2, b2, sd);
      }
    }
  }
  coarse_proj<<<16, 256, 0, stream>>>(cf, Wfp, fp_b, sfpb);
  coarse_scores<<<dim3(8,8), 256, 0, stream>>>(sfpb, sfpb + 131072, Zx);
  fill_border<<<3, 256, 0, stream>>>(Zx, bin_score);

  // ---- transport (persistent, sentinel dataflow — no barriers) ----
  transpose_k<<<dim3(17,17), 256, 0, stream>>>(Zx, Zt, ZDIM);
  transport_persist<<<TPNB, 1024, 0, stream>>>(Zx, Zt, Rr, Cc, UU, VV, out0,
                                               logf(1024.0f));

  // ---- local transformer (in-place, sequential-cross) ----
  gather_feats<<<512, 256, 0, stream>>>(src_final, tgt_final, patch_s, patch_t,
                                        node_corr, X0);
  for (int l = 0; l < 3; ++l){
    u16* wq = WlQ + (size_t)l*16384; u16* wk = WlK + (size_t)l*16384;
    u16* wv = WlV + (size_t)l*16384; u16* wm = WlM + (size_t)l*16384;
    u16* w1 = Wl1 + (size_t)l*65536; u16* w2 = Wl2 + (size_t)l*32768;
    const float* bq = l_bq + (size_t)l*128; const float* bk = l_bk + (size_t)l*128;
    const float* bv = l_bv + (size_t)l*128; const float* bm = l_bm + (size_t)l*128;
    const float* b1 = l_b1 + (size_t)l*256; const float* b2 = l_b2 + (size_t)l*128;
    if (!crossL[l]){
      local_layer<<<512, 256, 0, stream>>>(X0, 0, 0, wq,wk,wv,wm,w1,w2, bq,bk,bv,bm,b1,b2);
    } else {
      local_layer<<<256, 256, 0, stream>>>(X0, 1, 0, wq,wk,wv,wm,w1,w2, bq,bk,bv,bm,b1,b2);
      local_layer<<<256, 256, 0, stream>>>(X0, 1, 1, wq,wk,wv,wm,w1,w2, bq,bk,bv,bm,b1,b2);
    }
  }
  sk_fused<<<CC, 1024, 0, stream>>>(X0, Wlfp, lfp_b, node_corr, cnt_s, cnt_t, out_ls);

  // ---- GT ----
  gt_kernel<<<CC, 256, 0, stream>>>(src_raw, tgt_raw, rot, trans,
                                    patch_s, patch_t, node_corr, cnt_s, cnt_t, out_gt);

  (void)n_in; (void)out_size; (void)ws_size;
}